// Round 2
// baseline (2274.708 us; speedup 1.0000x reference)
//
#include <hip/hip_runtime.h>
#include <math.h>

// ---------------- constants ----------------
#define NN 50000
#define EE 800000
#define ETOT (EE + NN)
#define BB 128
#define DIM 128
#define GHID 32

struct CurvPack {
  float k[4], sk[4], mx[4];
};

// ---------------- device math helpers ----------------
__device__ __forceinline__ float wsum64(float v) {
#pragma unroll
  for (int m = 32; m; m >>= 1) v += __shfl_xor(v, m, 64);
  return v;
}

__device__ __forceinline__ float tan_k_d(float x, float kv, float sk) {
  if (kv > 0.f) return tanf(x * sk) / sk;
  if (kv < 0.f) return tanhf(x * sk) / sk;
  return x;
}

__device__ __forceinline__ float artan_k_d(float x, float kv, float sk) {
  if (kv > 0.f) return atanf(x * sk) / sk;
  if (kv < 0.f) {
    float t = x * sk;
    t = fminf(fmaxf(t, -1.f + 1e-7f), 1.f - 1e-7f);
    return atanhf(t) / sk;
  }
  return x;
}

__device__ __forceinline__ float proj_scale_d(float n, float kv, float maxn) {
  if (kv < 0.f && n > maxn) return maxn / n;
  return 1.f;
}

// ---------------- graph preprocessing ----------------
__global__ void k_init(const int* __restrict__ batch, float* __restrict__ deg,
                       float* __restrict__ counts, int n) {
  int i = blockIdx.x * 256 + threadIdx.x;
  if (i < n) {
    deg[i] = 1.0f;  // self loop
    atomicAdd(&counts[batch[i]], 1.0f);
  }
}

__global__ void k_deg(const int* __restrict__ ei, float* __restrict__ deg, int e) {
  int i = blockIdx.x * 256 + threadIdx.x;
  if (i < e) atomicAdd(&deg[ei[e + i]], 1.0f);  // col = edge_index[1]
}

__global__ void k_dinv(float* __restrict__ deg, int* __restrict__ ideg, int n) {
  int i = blockIdx.x * 256 + threadIdx.x;
  if (i < n) {
    float d = deg[i];
    ideg[i] = (int)(d + 0.5f);
    deg[i] = 1.0f / sqrtf(d);  // deg buffer becomes dinv
  }
}

// single-block exclusive scan of ideg -> off[0..n], cursor copy
__global__ void k_scan(const int* __restrict__ ideg, int* __restrict__ off,
                       int* __restrict__ cursor, int n) {
  __shared__ int wsh[16];
  int tid = threadIdx.x;
  int lane = tid & 63;
  int w = tid >> 6;
  int carry = 0;
  for (int base = 0; base < n; base += 1024) {
    int idx = base + tid;
    int v = (idx < n) ? ideg[idx] : 0;
    int x = v;
#pragma unroll
    for (int o2 = 1; o2 < 64; o2 <<= 1) {
      int t2 = __shfl_up(x, o2, 64);
      if (lane >= o2) x += t2;
    }
    if (lane == 63) wsh[w] = x;
    __syncthreads();
    if (tid < 16) {
      int s = wsh[tid];
#pragma unroll
      for (int o2 = 1; o2 < 16; o2 <<= 1) {
        int t2 = __shfl_up(s, o2, 64);
        if (lane >= o2) s += t2;
      }
      wsh[tid] = s;
    }
    __syncthreads();
    int woff = carry + (w ? wsh[w - 1] : 0);
    int incl = woff + x;
    if (idx < n) {
      off[idx] = incl - v;
      cursor[idx] = incl - v;
    }
    carry += wsh[15];
    __syncthreads();
  }
  if (tid == 0) off[n] = carry;
}

__global__ void k_place(const int* __restrict__ ei, const float* __restrict__ dinv,
                        int* __restrict__ cursor, int* __restrict__ csrsrc,
                        float* __restrict__ csrw, int e, int n) {
  int i = blockIdx.x * 256 + threadIdx.x;
  int et = e + n;
  if (i >= et) return;
  int r_, c_;
  if (i < e) {
    r_ = ei[i];
    c_ = ei[e + i];
  } else {
    r_ = i - e;
    c_ = i - e;
  }
  int p = atomicAdd(&cursor[c_], 1);
  csrsrc[p] = r_;
  csrw[p] = dinv[r_] * dinv[c_];
}

// ---------------- per-node prep: raw norm of x + all 4 expert expmap0 scales ----------------
__global__ void k_nodeprep(const float* __restrict__ x, float* __restrict__ scl,
                           float* __restrict__ xnk, int n, CurvPack cp) {
  int wid = blockIdx.x * 4 + (threadIdx.x >> 6);
  int lane = threadIdx.x & 63;
  if (wid >= n) return;
  float2 v = ((const float2*)x)[(size_t)wid * 64 + lane];
  float n2 = wsum64(v.x * v.x + v.y * v.y);
  float nraw = sqrtf(n2);
  if (lane < 4) {
    float kv = cp.k[lane], sk = cp.sk[lane], maxn = cp.mx[lane];
    float nnv = fmaxf(nraw, 1e-15f);
    float tk = tan_k_d(nnv, kv, sk);
    float s = tk / nnv;
    float pn = fmaxf(fabsf(tk) * (nraw / nnv), 1e-15f);
    float ps = proj_scale_d(pn, kv, maxn);
    scl[(size_t)lane * n + wid] = s * ps;
    xnk[(size_t)lane * n + wid] = pn * ps;
  }
}

// ---------------- bias points: expmap0(b) for all 8 (expert,layer) pairs ----------------
__global__ void k_biaspt_all(const float* __restrict__ eb1, const float* __restrict__ eb2,
                             float* __restrict__ biasb, CurvPack cp) {
  __shared__ float l2[2];
  int blk = blockIdx.x;  // ex*2 + layer
  int ex = blk >> 1, layer = blk & 1;
  float kv = cp.k[ex], sk = cp.sk[ex], maxn = cp.mx[ex];
  const float* b = (layer ? eb2 : eb1) + ex * 128;
  float* outb = biasb + blk * 132;
  int j = threadIdx.x;  // 0..127
  float v = b[j];
  float n2 = wsum64(v * v);
  if ((j & 63) == 0) l2[j >> 6] = n2;
  __syncthreads();
  n2 = l2[0] + l2[1];
  float nraw = sqrtf(n2);
  float nnv = fmaxf(nraw, 1e-15f);
  float tk = tan_k_d(nnv, kv, sk);
  float s = tk / nnv;
  float pn = fmaxf(fabsf(tk) * (nraw / nnv), 1e-15f);
  float ps = proj_scale_d(pn, kv, maxn);
  float bp = ps * s * v;
  outb[j] = bp;
  float y2v = wsum64(bp * bp);
  __syncthreads();
  if ((j & 63) == 0) l2[j >> 6] = y2v;
  __syncthreads();
  if (j == 0) outb[128] = l2[0] + l2[1];
}

// ---------------- expert GEMM + mobius pointwise -> t ----------------
// BM=64 nodes, 128 outs, K=128 in two chunks of 64. block=256.
// scale != nullptr: apply per-node scalar during staging (fused expmap0).
__global__ __launch_bounds__(256) void k_matpre(
    const float* __restrict__ xmx, const float* __restrict__ scale,
    const float* __restrict__ xnorm, const float* __restrict__ W,
    const float* __restrict__ biasb, float* __restrict__ tout, int n, float kv, float sk,
    float maxn) {
  __shared__ float xT[64][68];
  __shared__ float Wt[64][132];
  int tid = threadIdx.x;
  int n0 = blockIdx.x * 64;
  int c = tid & 15, r = tid >> 4;

  float acc[4][8];
#pragma unroll
  for (int i = 0; i < 4; i++)
#pragma unroll
    for (int jj = 0; jj < 8; jj++) acc[i][jj] = 0.f;

  for (int kc = 0; kc < 2; kc++) {
    if (kc) __syncthreads();
#pragma unroll
    for (int it = 0; it < 32; it++) {
      int u = tid + it * 256;
      int j = u >> 6, kd = u & 63;
      Wt[kd][j] = W[j * 128 + kc * 64 + kd];
    }
#pragma unroll
    for (int it = 0; it < 4; it++) {
      int u = tid + it * 256;
      int node = u >> 4, c4 = u & 15;
      float4 v = make_float4(0.f, 0.f, 0.f, 0.f);
      if (n0 + node < n) {
        v = ((const float4*)xmx)[(size_t)(n0 + node) * 32 + kc * 16 + c4];
        if (scale) {
          float sc = scale[n0 + node];
          v.x *= sc; v.y *= sc; v.z *= sc; v.w *= sc;
        }
      }
      xT[4 * c4 + 0][node] = v.x;
      xT[4 * c4 + 1][node] = v.y;
      xT[4 * c4 + 2][node] = v.z;
      xT[4 * c4 + 3][node] = v.w;
    }
    __syncthreads();
#pragma unroll 8
    for (int kd = 0; kd < 64; kd++) {
      float4 av = *(const float4*)&xT[kd][r * 4];
      float4 b0 = *(const float4*)&Wt[kd][c * 8];
      float4 b1 = *(const float4*)&Wt[kd][c * 8 + 4];
      float a[4] = {av.x, av.y, av.z, av.w};
      float bbv[8] = {b0.x, b0.y, b0.z, b0.w, b1.x, b1.y, b1.z, b1.w};
#pragma unroll
      for (int i = 0; i < 4; i++)
#pragma unroll
        for (int jj = 0; jj < 8; jj++) acc[i][jj] = fmaf(a[i], bbv[jj], acc[i][jj]);
    }
  }

  // ---- pointwise: mobius_matvec post + mobius_add(bias) + logmap0 ----
  float bp[8];
#pragma unroll
  for (int jj = 0; jj < 8; jj++) bp[jj] = biasb[c * 8 + jj];
  float y2 = biasb[128];

  float mxn2[4], sab[4], mbp[4];
#pragma unroll
  for (int i = 0; i < 4; i++) {
    float s0 = 0.f, s1 = 0.f, s2v = 0.f;
#pragma unroll
    for (int jj = 0; jj < 8; jj++) {
      float v = acc[i][jj];
      s0 = fmaf(v, v, s0);
      s1 += fabsf(v);
      s2v = fmaf(v, bp[jj], s2v);
    }
    mxn2[i] = s0;
    sab[i] = s1;
    mbp[i] = s2v;
  }
#pragma unroll
  for (int m = 1; m < 16; m <<= 1) {
#pragma unroll
    for (int i = 0; i < 4; i++) {
      mxn2[i] += __shfl_xor(mxn2[i], m, 64);
      sab[i] += __shfl_xor(sab[i], m, 64);
      mbp[i] += __shfl_xor(mbp[i], m, 64);
    }
  }

  float As[4], Cs[4];
#pragma unroll
  for (int i = 0; i < 4; i++) {
    int node = n0 + r * 4 + i;
    float xnr = xnorm[node < n ? node : (n - 1)];
    float xn = fmaxf(xnr, 1e-15f);
    float mxraw = sqrtf(mxn2[i]);
    float mxv = fmaxf(mxraw, 1e-15f);
    float ar = artan_k_d(xn, kv, sk);
    float c1 = tan_k_d(mxv / xn * ar, kv, sk);
    float s = (sab[i] == 0.f) ? 0.f : c1 / mxv;
    float pn = fmaxf(fabsf(c1) * (mxraw / mxv), 1e-15f);
    float ps = (sab[i] == 0.f) ? 1.f : proj_scale_d(pn, kv, maxn);
    s *= ps;
    float x2 = (s * s) * mxn2[i];
    float xy = s * mbp[i];
    float A = 1.f - 2.f * kv * xy - kv * y2;
    float Cc = 1.f + kv * x2;
    float den = fmaxf(1.f - 2.f * kv * xy + (kv * kv) * x2 * y2, 1e-15f);
    As[i] = A * s / den;
    Cs[i] = Cc / den;
  }

  float hb[4][8];
  float hb2[4];
#pragma unroll
  for (int i = 0; i < 4; i++) {
    float s0 = 0.f;
#pragma unroll
    for (int jj = 0; jj < 8; jj++) {
      float v = fmaf(As[i], acc[i][jj], Cs[i] * bp[jj]);
      hb[i][jj] = v;
      s0 = fmaf(v, v, s0);
    }
    hb2[i] = s0;
  }
#pragma unroll
  for (int m = 1; m < 16; m <<= 1) {
#pragma unroll
    for (int i = 0; i < 4; i++) hb2[i] += __shfl_xor(hb2[i], m, 64);
  }

#pragma unroll
  for (int i = 0; i < 4; i++) {
    int node = n0 + r * 4 + i;
    if (node >= n) continue;
    float nraw = sqrtf(hb2[i]);
    float ps2 = proj_scale_d(fmaxf(nraw, 1e-15f), kv, maxn);
    float nh = fmaxf(ps2 * nraw, 1e-15f);
    float L = artan_k_d(nh, kv, sk) / nh * ps2;
    float4 o0 = make_float4(L * hb[i][0], L * hb[i][1], L * hb[i][2], L * hb[i][3]);
    float4 o1 = make_float4(L * hb[i][4], L * hb[i][5], L * hb[i][6], L * hb[i][7]);
    float4* dst = (float4*)tout + (size_t)node * 32 + c * 2;
    dst[0] = o0;
    dst[1] = o1;
  }
}

// ---------------- CSR aggregation + expmap0 epilogue (dim 128) ----------------
// Wave per node; two 32-lane halves process 2 edges concurrently (float4/lane),
// unrolled 4 pairs -> 8 edges / 4 loads in flight per round.
// POOL=0: write xm + xnorm.  POOL=1: fuse logmap0 + batch pooling into feats.
template <int POOL>
__global__ void k_aggexp(const float* __restrict__ t, const int* __restrict__ off,
                         const int* __restrict__ src, const float* __restrict__ wgt,
                         float* __restrict__ xm, float* __restrict__ xnorm,
                         const int* __restrict__ batch, float* __restrict__ feats,
                         int ex, int n, float kv, float sk, float maxn) {
  int wid = blockIdx.x * 4 + (threadIdx.x >> 6);
  int lane = threadIdx.x & 63;
  if (wid >= n) return;
  int half = lane >> 5, l32 = lane & 31;
  int e0 = off[wid], e1 = off[wid + 1];
  float4 acc = make_float4(0.f, 0.f, 0.f, 0.f);
  for (int base = e0; base < e1; base += 64) {
    int idx = base + lane;
    int sv = (idx < e1) ? src[idx] : 0;
    float wv = (idx < e1) ? wgt[idx] : 0.f;
    int cnt = min(64, e1 - base);
    int tq = 0;
    for (; tq + 8 <= cnt; tq += 8) {
      int ss[4];
      float ww[4];
#pragma unroll
      for (int q = 0; q < 4; q++) {
        int eidx = tq + 2 * q + half;
        ss[q] = __shfl(sv, eidx, 64);
        ww[q] = __shfl(wv, eidx, 64);
      }
#pragma unroll
      for (int q = 0; q < 4; q++) {
        float4 tv = ((const float4*)t)[(size_t)ss[q] * 32 + l32];
        acc.x = fmaf(ww[q], tv.x, acc.x);
        acc.y = fmaf(ww[q], tv.y, acc.y);
        acc.z = fmaf(ww[q], tv.z, acc.z);
        acc.w = fmaf(ww[q], tv.w, acc.w);
      }
    }
    for (; tq < cnt; tq += 2) {
      int e2 = tq + half;
      int ss = __shfl(sv, e2 & 63, 64);
      float ww = __shfl(wv, e2 & 63, 64);
      if (e2 >= cnt) ww = 0.f;
      float4 tv = ((const float4*)t)[(size_t)ss * 32 + l32];
      acc.x = fmaf(ww, tv.x, acc.x);
      acc.y = fmaf(ww, tv.y, acc.y);
      acc.z = fmaf(ww, tv.z, acc.z);
      acc.w = fmaf(ww, tv.w, acc.w);
    }
  }
  // merge the two halves (lanes i and i^32 then hold identical values)
  acc.x += __shfl_xor(acc.x, 32, 64);
  acc.y += __shfl_xor(acc.y, 32, 64);
  acc.z += __shfl_xor(acc.z, 32, 64);
  acc.w += __shfl_xor(acc.w, 32, 64);
  float dot = fmaf(acc.x, acc.x, fmaf(acc.y, acc.y, fmaf(acc.z, acc.z, acc.w * acc.w)));
  float n2 = wsum64(dot) * 0.5f;  // halves duplicated -> exact 2x
  float nraw = sqrtf(n2);
  float nnv = fmaxf(nraw, 1e-15f);
  float tk = tan_k_d(nnv, kv, sk);
  float s = tk / nnv;
  float pn = fmaxf(fabsf(tk) * (nraw / nnv), 1e-15f);
  float ps = proj_scale_d(pn, kv, maxn);
  s *= ps;
  if (POOL == 0) {
    if (half == 0) {
      float4 o = make_float4(s * acc.x, s * acc.y, s * acc.z, s * acc.w);
      ((float4*)xm)[(size_t)wid * 32 + l32] = o;
    }
    if (lane == 0) xnorm[wid] = pn * ps;
  } else {
    float nh = fmaxf(pn * ps, 1e-15f);
    float sc = artan_k_d(nh, kv, sk) / nh * s;
    if (half == 0) {
      int b = batch[wid];
      float* dst = &feats[(size_t)b * 512 + ex * 128 + 4 * l32];
      atomicAdd(dst + 0, sc * acc.x);
      atomicAdd(dst + 1, sc * acc.y);
      atomicAdd(dst + 2, sc * acc.z);
      atomicAdd(dst + 3, sc * acc.w);
    }
  }
}

// ---------------- gate GEMM 1: m1 = x @ gw1.T  [N,128] -> [N,32] ----------------
__global__ __launch_bounds__(256) void k_gate1(const float* __restrict__ x,
                                               const float* __restrict__ gw1,
                                               float* __restrict__ m1, int n) {
  __shared__ float xT[64][68];
  __shared__ float Wt[64][36];
  int tid = threadIdx.x;
  int n0 = blockIdx.x * 64;
  int c = tid & 7, r = tid >> 3;  // c: 4 outs, r: 2 nodes (r<32)
  float acc[2][4];
#pragma unroll
  for (int i = 0; i < 2; i++)
#pragma unroll
    for (int jj = 0; jj < 4; jj++) acc[i][jj] = 0.f;

  for (int kc = 0; kc < 2; kc++) {
    if (kc) __syncthreads();
#pragma unroll
    for (int it = 0; it < 8; it++) {
      int u = tid + it * 256;
      int j = u >> 6, kd = u & 63;
      Wt[kd][j] = gw1[j * 128 + kc * 64 + kd];
    }
#pragma unroll
    for (int it = 0; it < 4; it++) {
      int u = tid + it * 256;
      int node = u >> 4, c4 = u & 15;
      float4 v = make_float4(0.f, 0.f, 0.f, 0.f);
      if (n0 + node < n) v = ((const float4*)x)[(size_t)(n0 + node) * 32 + kc * 16 + c4];
      xT[4 * c4 + 0][node] = v.x;
      xT[4 * c4 + 1][node] = v.y;
      xT[4 * c4 + 2][node] = v.z;
      xT[4 * c4 + 3][node] = v.w;
    }
    __syncthreads();
#pragma unroll 8
    for (int kd = 0; kd < 64; kd++) {
      float2 av = *(const float2*)&xT[kd][r * 2];
      float4 bv = *(const float4*)&Wt[kd][c * 4];
      float a[2] = {av.x, av.y};
      float bbv[4] = {bv.x, bv.y, bv.z, bv.w};
#pragma unroll
      for (int i = 0; i < 2; i++)
#pragma unroll
        for (int jj = 0; jj < 4; jj++) acc[i][jj] = fmaf(a[i], bbv[jj], acc[i][jj]);
    }
  }
#pragma unroll
  for (int i = 0; i < 2; i++) {
    int node = n0 + r * 2 + i;
    if (node >= n) continue;
    ((float4*)m1)[(size_t)node * 8 + c] = make_float4(acc[i][0], acc[i][1], acc[i][2], acc[i][3]);
  }
}

// ---------------- gate GEMM 2: m2 = g1 @ gw2.T  [N,32] -> [N,128] ----------------
__global__ __launch_bounds__(256) void k_gate2(const float* __restrict__ g1,
                                               const float* __restrict__ gw2,
                                               float* __restrict__ m2, int n) {
  __shared__ float xT[32][68];
  __shared__ float Wt[32][132];
  int tid = threadIdx.x;
  int n0 = blockIdx.x * 64;
  int c = tid & 15, r = tid >> 4;  // c: 8 outs, r: 4 nodes (r<16)
  float acc[4][8];
#pragma unroll
  for (int i = 0; i < 4; i++)
#pragma unroll
    for (int jj = 0; jj < 8; jj++) acc[i][jj] = 0.f;

#pragma unroll
  for (int it = 0; it < 16; it++) {
    int u = tid + it * 256;
    int j = u >> 5, kd = u & 31;
    Wt[kd][j] = gw2[j * 32 + kd];
  }
#pragma unroll
  for (int it = 0; it < 2; it++) {
    int u = tid + it * 256;
    int node = u >> 3, c4 = u & 7;
    float4 v = make_float4(0.f, 0.f, 0.f, 0.f);
    if (n0 + node < n) v = ((const float4*)g1)[(size_t)(n0 + node) * 8 + c4];
    xT[4 * c4 + 0][node] = v.x;
    xT[4 * c4 + 1][node] = v.y;
    xT[4 * c4 + 2][node] = v.z;
    xT[4 * c4 + 3][node] = v.w;
  }
  __syncthreads();
#pragma unroll 8
  for (int kd = 0; kd < 32; kd++) {
    float4 av = *(const float4*)&xT[kd][r * 4];
    float4 b0 = *(const float4*)&Wt[kd][c * 8];
    float4 b1 = *(const float4*)&Wt[kd][c * 8 + 4];
    float a[4] = {av.x, av.y, av.z, av.w};
    float bbv[8] = {b0.x, b0.y, b0.z, b0.w, b1.x, b1.y, b1.z, b1.w};
#pragma unroll
    for (int i = 0; i < 4; i++)
#pragma unroll
      for (int jj = 0; jj < 8; jj++) acc[i][jj] = fmaf(a[i], bbv[jj], acc[i][jj]);
  }
#pragma unroll
  for (int i = 0; i < 4; i++) {
    int node = n0 + r * 4 + i;
    if (node >= n) continue;
    float4* dst = (float4*)m2 + (size_t)node * 32 + c * 2;
    dst[0] = make_float4(acc[i][0], acc[i][1], acc[i][2], acc[i][3]);
    dst[1] = make_float4(acc[i][4], acc[i][5], acc[i][6], acc[i][7]);
  }
}

// ---------------- gate aggregation dim32 + bias + relu ----------------
// Wave per node; 8 groups of 8 lanes process 8 edges concurrently (float4/lane).
__global__ void k_agg_relu32(const float* __restrict__ m1, const int* __restrict__ off,
                             const int* __restrict__ src, const float* __restrict__ wgt,
                             const float* __restrict__ bias, float* __restrict__ g1, int n) {
  int node = blockIdx.x * 4 + (threadIdx.x >> 6);
  int lane = threadIdx.x & 63;
  if (node >= n) return;
  int grp = lane >> 3, l8 = lane & 7;
  int e0 = off[node], e1 = off[node + 1];
  float4 acc = make_float4(0.f, 0.f, 0.f, 0.f);
  for (int base = e0; base < e1; base += 64) {
    int idx = base + lane;
    int sv = (idx < e1) ? src[idx] : 0;
    float wv = (idx < e1) ? wgt[idx] : 0.f;
    int cnt = min(64, e1 - base);
    int tq = 0;
    for (; tq + 8 <= cnt; tq += 8) {
      int eidx = tq + grp;
      int ss = __shfl(sv, eidx, 64);
      float ww = __shfl(wv, eidx, 64);
      float4 tv = ((const float4*)m1)[(size_t)ss * 8 + l8];
      acc.x = fmaf(ww, tv.x, acc.x);
      acc.y = fmaf(ww, tv.y, acc.y);
      acc.z = fmaf(ww, tv.z, acc.z);
      acc.w = fmaf(ww, tv.w, acc.w);
    }
    if (tq < cnt) {
      int e2 = tq + grp;
      int ss = __shfl(sv, e2 & 63, 64);
      float ww = __shfl(wv, e2 & 63, 64);
      if (e2 >= cnt) ww = 0.f;
      float4 tv = ((const float4*)m1)[(size_t)ss * 8 + l8];
      acc.x = fmaf(ww, tv.x, acc.x);
      acc.y = fmaf(ww, tv.y, acc.y);
      acc.z = fmaf(ww, tv.z, acc.z);
      acc.w = fmaf(ww, tv.w, acc.w);
    }
  }
#pragma unroll
  for (int m = 8; m <= 32; m <<= 1) {
    acc.x += __shfl_xor(acc.x, m, 64);
    acc.y += __shfl_xor(acc.y, m, 64);
    acc.z += __shfl_xor(acc.z, m, 64);
    acc.w += __shfl_xor(acc.w, m, 64);
  }
  if (grp == 0) {
    float4 bb = ((const float4*)bias)[l8];
    float4 o = make_float4(fmaxf(acc.x + bb.x, 0.f), fmaxf(acc.y + bb.y, 0.f),
                           fmaxf(acc.z + bb.z, 0.f), fmaxf(acc.w + bb.w, 0.f));
    ((float4*)g1)[(size_t)node * 8 + l8] = o;
  }
}

// ---------------- gate aggregation dim128 + bias + relu + pooling ----------------
__global__ void k_agg_relu_pool(const float* __restrict__ m2, const int* __restrict__ off,
                                const int* __restrict__ src, const float* __restrict__ wgt,
                                const float* __restrict__ bias, const int* __restrict__ batch,
                                float* __restrict__ hgate, int n) {
  int wid = blockIdx.x * 4 + (threadIdx.x >> 6);
  int lane = threadIdx.x & 63;
  if (wid >= n) return;
  int half = lane >> 5, l32 = lane & 31;
  int e0 = off[wid], e1 = off[wid + 1];
  float4 acc = make_float4(0.f, 0.f, 0.f, 0.f);
  for (int base = e0; base < e1; base += 64) {
    int idx = base + lane;
    int sv = (idx < e1) ? src[idx] : 0;
    float wv = (idx < e1) ? wgt[idx] : 0.f;
    int cnt = min(64, e1 - base);
    int tq = 0;
    for (; tq + 8 <= cnt; tq += 8) {
      int ss[4];
      float ww[4];
#pragma unroll
      for (int q = 0; q < 4; q++) {
        int eidx = tq + 2 * q + half;
        ss[q] = __shfl(sv, eidx, 64);
        ww[q] = __shfl(wv, eidx, 64);
      }
#pragma unroll
      for (int q = 0; q < 4; q++) {
        float4 tv = ((const float4*)m2)[(size_t)ss[q] * 32 + l32];
        acc.x = fmaf(ww[q], tv.x, acc.x);
        acc.y = fmaf(ww[q], tv.y, acc.y);
        acc.z = fmaf(ww[q], tv.z, acc.z);
        acc.w = fmaf(ww[q], tv.w, acc.w);
      }
    }
    for (; tq < cnt; tq += 2) {
      int e2 = tq + half;
      int ss = __shfl(sv, e2 & 63, 64);
      float ww = __shfl(wv, e2 & 63, 64);
      if (e2 >= cnt) ww = 0.f;
      float4 tv = ((const float4*)m2)[(size_t)ss * 32 + l32];
      acc.x = fmaf(ww, tv.x, acc.x);
      acc.y = fmaf(ww, tv.y, acc.y);
      acc.z = fmaf(ww, tv.z, acc.z);
      acc.w = fmaf(ww, tv.w, acc.w);
    }
  }
  acc.x += __shfl_xor(acc.x, 32, 64);
  acc.y += __shfl_xor(acc.y, 32, 64);
  acc.z += __shfl_xor(acc.z, 32, 64);
  acc.w += __shfl_xor(acc.w, 32, 64);
  if (half == 0) {
    float4 bb = ((const float4*)bias)[l32];
    int b = batch[wid];
    float* dst = &hgate[(size_t)b * 128 + 4 * l32];
    atomicAdd(dst + 0, fmaxf(acc.x + bb.x, 0.f));
    atomicAdd(dst + 1, fmaxf(acc.y + bb.y, 0.f));
    atomicAdd(dst + 2, fmaxf(acc.z + bb.z, 0.f));
    atomicAdd(dst + 3, fmaxf(acc.w + bb.w, 0.f));
  }
}

// ---------------- final: distance gate + softmax + outputs ----------------
__global__ __launch_bounds__(128) void k_final(const float* __restrict__ feats,
                                               const float* __restrict__ hgate,
                                               const float* __restrict__ counts,
                                               const float* __restrict__ gate_u,
                                               const float* __restrict__ tau_raw,
                                               float* __restrict__ out, CurvPack cp) {
  __shared__ float l2[2];
  int b = blockIdx.x;
  int j = threadIdx.x;
  float cnt = fmaxf(counts[b], 1.f);
  float hg = hgate[(size_t)b * 128 + j] / cnt;

  auto bsum = [&](float v) -> float {
    v = wsum64(v);
    __syncthreads();
    if ((j & 63) == 0) l2[j >> 6] = v;
    __syncthreads();
    return l2[0] + l2[1];
  };

  float nhg2 = bsum(hg * hg);
  float nhgraw = sqrtf(nhg2);
  float nhg = fmaxf(nhgraw, 1e-15f);

  float d[4], tau[4];
#pragma unroll
  for (int i = 0; i < 4; i++) {
    float kv = cp.k[i], sk = cp.sk[i], mxn = cp.mx[i];
    float tk = tan_k_d(nhg, kv, sk);
    float s = tk / nhg;
    float pn = fmaxf(fabsf(tk) * (nhgraw / nhg), 1e-15f);
    s *= proj_scale_d(pn, kv, mxn);
    float zk = s * hg;

    float u = gate_u[i * 128 + j];
    float nu2 = bsum(u * u);
    float nuraw = sqrtf(nu2);
    float nu = fmaxf(nuraw, 1e-15f);
    float tku = tan_k_d(nu, kv, sk);
    float su = tku / nu;
    float pnu = fmaxf(fabsf(tku) * (nuraw / nu), 1e-15f);
    su *= proj_scale_d(pnu, kv, mxn);
    float yk = su * u;

    float xv = -zk;
    float x2 = bsum(xv * xv);
    float y2 = bsum(yk * yk);
    float xy = bsum(xv * yk);
    float A = 1.f - 2.f * kv * xy - kv * y2;
    float C = 1.f + kv * x2;
    float den = fmaxf(1.f - 2.f * kv * xy + (kv * kv) * x2 * y2, 1e-15f);
    float ma = (A * xv + C * yk) / den;
    float m2 = bsum(ma * ma);
    float mraw = sqrtf(m2);
    float ps2 = proj_scale_d(fmaxf(mraw, 1e-15f), kv, mxn);
    float nm = fmaxf(ps2 * mraw, 1e-15f);
    d[i] = 2.f * artan_k_d(nm, kv, sk);

    float tr = tau_raw[i];
    tau[i] = fminf(fmaxf(log1pf(expf(tr)) + 0.05f, 0.05f), 10.f);
  }

  // softmax(-d/tau)
  float xi[4];
  float mxv = -1e30f;
#pragma unroll
  for (int i = 0; i < 4; i++) {
    xi[i] = -d[i] / tau[i];
    mxv = fmaxf(mxv, xi[i]);
  }
  float es = 0.f, e[4];
#pragma unroll
  for (int i = 0; i < 4; i++) {
    e[i] = expf(xi[i] - mxv);
    es += e[i];
  }
  float w[4];
#pragma unroll
  for (int i = 0; i < 4; i++) w[i] = e[i] / es;

#pragma unroll
  for (int i = 0; i < 4; i++)
    out[(size_t)b * 512 + i * 128 + j] = feats[(size_t)b * 512 + i * 128 + j] / cnt * w[i];

  if (j < 4) {
    out[65536 + b * 4 + j] = w[j];
    out[66048 + b * 4 + j] = d[j];
  }
  if (b == 0 && j < 4) out[66560 + j] = tau[j];
}

// ---------------- host launcher ----------------
extern "C" void kernel_launch(void* const* d_in, const int* in_sizes, int n_in,
                              void* d_out, int out_size, void* d_ws, size_t ws_size,
                              hipStream_t stream) {
  const float* x = (const float*)d_in[0];
  const int* ei = (const int*)d_in[1];
  const int* batch = (const int*)d_in[2];
  const float* ew1 = (const float*)d_in[3];
  const float* eb1 = (const float*)d_in[4];
  const float* ew2 = (const float*)d_in[5];
  const float* eb2 = (const float*)d_in[6];
  const float* gw1 = (const float*)d_in[7];
  const float* gb1 = (const float*)d_in[8];
  const float* gw2 = (const float*)d_in[9];
  const float* gb2 = (const float*)d_in[10];
  const float* gu = (const float*)d_in[11];
  const float* traw = (const float*)d_in[12];
  float* out = (float*)d_out;

  const int N = NN, E = EE, ET = ETOT, B = BB;

  float* ws = (float*)d_ws;
  size_t o = 0;
  float* xm = ws;           o += (size_t)N * 128;
  float* tb = ws + o;       o += (size_t)N * 128;
  float* deg = ws + o;      o += N;  // becomes dinv
  float* xnorm = ws + o;    o += N;
  float* csrw = ws + o;     o += ET;
  float* counts = ws + o;   o += 256;
  float* feats = ws + o;    o += (size_t)B * 512;
  float* hg = ws + o;       o += (size_t)B * 128;
  float* biasb = ws + o;    o += 8 * 132;
  float* scl = ws + o;      o += (size_t)4 * N;
  float* xnk = ws + o;      o += (size_t)4 * N;
  int* ideg = (int*)(ws + o);   o += N;
  int* csroff = (int*)(ws + o); o += N + 8;
  int* cursor = (int*)(ws + o); o += N;
  int* csrsrc = (int*)(ws + o); o += ET;

  // zero: counts + feats + hg (contiguous)
  hipMemsetAsync(counts, 0, (256 + (size_t)B * 512 + (size_t)B * 128) * sizeof(float), stream);

  const double curvs[4] = {-1.0, 0.0, 1.0, -0.5};
  CurvPack cp;
  for (int i = 0; i < 4; i++) {
    double kd = curvs[i];
    double skd = sqrt(fabs(kd));
    cp.k[i] = (float)kd;
    cp.sk[i] = (float)skd;
    cp.mx[i] = (kd < 0) ? (float)((1.0 - 1e-5) / skd) : 3.0e38f;
  }

  k_init<<<(N + 255) / 256, 256, 0, stream>>>(batch, deg, counts, N);
  k_deg<<<(E + 255) / 256, 256, 0, stream>>>(ei, deg, E);
  k_dinv<<<(N + 255) / 256, 256, 0, stream>>>(deg, ideg, N);
  k_scan<<<1, 1024, 0, stream>>>(ideg, csroff, cursor, N);
  k_place<<<(ET + 255) / 256, 256, 0, stream>>>(ei, deg, cursor, csrsrc, csrw, E, N);
  k_nodeprep<<<(N + 3) / 4, 256, 0, stream>>>(x, scl, xnk, N, cp);
  k_biaspt_all<<<8, 128, 0, stream>>>(eb1, eb2, biasb, cp);

  for (int ex = 0; ex < 4; ex++) {
    float kv = cp.k[ex], sk = cp.sk[ex], mxn = cp.mx[ex];
    // layer 1: fused expmap0 via per-node scale
    k_matpre<<<(N + 63) / 64, 256, 0, stream>>>(x, scl + (size_t)ex * N, xnk + (size_t)ex * N,
                                                ew1 + (size_t)ex * 16384, biasb + (ex * 2) * 132,
                                                tb, N, kv, sk, mxn);
    k_aggexp<0><<<(N + 3) / 4, 256, 0, stream>>>(tb, csroff, csrsrc, csrw, xm, xnorm,
                                                 nullptr, nullptr, 0, N, kv, sk, mxn);
    // layer 2
    k_matpre<<<(N + 63) / 64, 256, 0, stream>>>(xm, nullptr, xnorm, ew2 + (size_t)ex * 16384,
                                                biasb + (ex * 2 + 1) * 132, tb, N, kv, sk, mxn);
    k_aggexp<1><<<(N + 3) / 4, 256, 0, stream>>>(tb, csroff, csrsrc, csrw, nullptr, nullptr,
                                                 batch, feats, ex, N, kv, sk, mxn);
  }

  // gate GCN
  k_gate1<<<(N + 63) / 64, 256, 0, stream>>>(x, gw1, tb, N);
  k_agg_relu32<<<(N + 3) / 4, 256, 0, stream>>>(tb, csroff, csrsrc, csrw, gb1, xm, N);
  k_gate2<<<(N + 63) / 64, 256, 0, stream>>>(xm, gw2, tb, N);
  k_agg_relu_pool<<<(N + 3) / 4, 256, 0, stream>>>(tb, csroff, csrsrc, csrw, gb2, batch, hg, N);

  k_final<<<B, 128, 0, stream>>>(feats, hg, counts, gu, traw, out, cp);

  (void)in_sizes; (void)n_in; (void)out_size; (void)ws_size;
}

// Round 3
// 2215.629 us; speedup vs baseline: 1.0267x; 1.0267x over previous
//
#include <hip/hip_runtime.h>
#include <math.h>

// ---------------- constants ----------------
#define NN 50000
#define EE 800000
#define ETOT (EE + NN)
#define BB 128
#define DIM 128
#define GHID 32
#define CHUNK 128

struct CurvPack {
  float k[4], sk[4], mx[4];
};

// ---------------- device math helpers ----------------
__device__ __forceinline__ float wsum64(float v) {
#pragma unroll
  for (int m = 32; m; m >>= 1) v += __shfl_xor(v, m, 64);
  return v;
}

__device__ __forceinline__ float tan_k_d(float x, float kv, float sk) {
  if (kv > 0.f) return tanf(x * sk) / sk;
  if (kv < 0.f) return tanhf(x * sk) / sk;
  return x;
}

__device__ __forceinline__ float artan_k_d(float x, float kv, float sk) {
  if (kv > 0.f) return atanf(x * sk) / sk;
  if (kv < 0.f) {
    float t = x * sk;
    t = fminf(fmaxf(t, -1.f + 1e-7f), 1.f - 1e-7f);
    return atanhf(t) / sk;
  }
  return x;
}

__device__ __forceinline__ float proj_scale_d(float n, float kv, float maxn) {
  if (kv < 0.f && n > maxn) return maxn / n;
  return 1.f;
}

// ---------------- graph preprocessing ----------------
__global__ void k_init(const int* __restrict__ batch, float* __restrict__ deg,
                       float* __restrict__ counts, int n) {
  int i = blockIdx.x * 256 + threadIdx.x;
  if (i < n) {
    deg[i] = 1.0f;  // self loop
    atomicAdd(&counts[batch[i]], 1.0f);
  }
}

__global__ void k_deg(const int* __restrict__ ei, float* __restrict__ deg, int e) {
  int i = blockIdx.x * 256 + threadIdx.x;
  if (i < e) atomicAdd(&deg[ei[e + i]], 1.0f);  // col = edge_index[1]
}

__global__ void k_dinv(float* __restrict__ deg, int* __restrict__ ideg, int n) {
  int i = blockIdx.x * 256 + threadIdx.x;
  if (i < n) {
    float d = deg[i];
    ideg[i] = (int)(d + 0.5f);
    deg[i] = 1.0f / sqrtf(d);  // deg buffer becomes dinv
  }
}

// single-block exclusive scan of ideg -> off[0..n], cursor copy
__global__ void k_scan(const int* __restrict__ ideg, int* __restrict__ off,
                       int* __restrict__ cursor, int n) {
  __shared__ int wsh[16];
  int tid = threadIdx.x;
  int lane = tid & 63;
  int w = tid >> 6;
  int carry = 0;
  for (int base = 0; base < n; base += 1024) {
    int idx = base + tid;
    int v = (idx < n) ? ideg[idx] : 0;
    int x = v;
#pragma unroll
    for (int o2 = 1; o2 < 64; o2 <<= 1) {
      int t2 = __shfl_up(x, o2, 64);
      if (lane >= o2) x += t2;
    }
    if (lane == 63) wsh[w] = x;
    __syncthreads();
    if (tid < 16) {
      int s = wsh[tid];
#pragma unroll
      for (int o2 = 1; o2 < 16; o2 <<= 1) {
        int t2 = __shfl_up(s, o2, 64);
        if (lane >= o2) s += t2;
      }
      wsh[tid] = s;
    }
    __syncthreads();
    int woff = carry + (w ? wsh[w - 1] : 0);
    int incl = woff + x;
    if (idx < n) {
      off[idx] = incl - v;
      cursor[idx] = incl - v;
    }
    carry += wsh[15];
    __syncthreads();
  }
  if (tid == 0) off[n] = carry;
}

// place edges: esw[p] = (src, weight_bits) at dst-sorted position
__global__ void k_place(const int* __restrict__ ei, const float* __restrict__ dinv,
                        int* __restrict__ cursor, int2* __restrict__ esw, int e, int n) {
  int i = blockIdx.x * 256 + threadIdx.x;
  int et = e + n;
  if (i >= et) return;
  int r_, c_;
  if (i < e) {
    r_ = ei[i];
    c_ = ei[e + i];
  } else {
    r_ = i - e;
    c_ = i - e;
  }
  int p = atomicAdd(&cursor[c_], 1);
  esw[p] = make_int2(r_, __float_as_int(dinv[r_] * dinv[c_]));
}

// ---------------- per-node prep: raw norm of x + all 4 expert expmap0 scales ----------------
__global__ void k_nodeprep(const float* __restrict__ x, float* __restrict__ scl,
                           float* __restrict__ xnk, int n, CurvPack cp) {
  int wid = blockIdx.x * 4 + (threadIdx.x >> 6);
  int lane = threadIdx.x & 63;
  if (wid >= n) return;
  float2 v = ((const float2*)x)[(size_t)wid * 64 + lane];
  float n2 = wsum64(v.x * v.x + v.y * v.y);
  float nraw = sqrtf(n2);
  if (lane < 4) {
    float kv = cp.k[lane], sk = cp.sk[lane], maxn = cp.mx[lane];
    float nnv = fmaxf(nraw, 1e-15f);
    float tk = tan_k_d(nnv, kv, sk);
    float s = tk / nnv;
    float pn = fmaxf(fabsf(tk) * (nraw / nnv), 1e-15f);
    float ps = proj_scale_d(pn, kv, maxn);
    scl[(size_t)lane * n + wid] = s * ps;
    xnk[(size_t)lane * n + wid] = pn * ps;
  }
}

// ---------------- bias points: expmap0(b) for all 8 (expert,layer) pairs ----------------
__global__ void k_biaspt_all(const float* __restrict__ eb1, const float* __restrict__ eb2,
                             float* __restrict__ biasb, CurvPack cp) {
  __shared__ float l2[2];
  int blk = blockIdx.x;  // ex*2 + layer
  int ex = blk >> 1, layer = blk & 1;
  float kv = cp.k[ex], sk = cp.sk[ex], maxn = cp.mx[ex];
  const float* b = (layer ? eb2 : eb1) + ex * 128;
  float* outb = biasb + blk * 132;
  int j = threadIdx.x;  // 0..127
  float v = b[j];
  float n2 = wsum64(v * v);
  if ((j & 63) == 0) l2[j >> 6] = n2;
  __syncthreads();
  n2 = l2[0] + l2[1];
  float nraw = sqrtf(n2);
  float nnv = fmaxf(nraw, 1e-15f);
  float tk = tan_k_d(nnv, kv, sk);
  float s = tk / nnv;
  float pn = fmaxf(fabsf(tk) * (nraw / nnv), 1e-15f);
  float ps = proj_scale_d(pn, kv, maxn);
  float bp = ps * s * v;
  outb[j] = bp;
  float y2v = wsum64(bp * bp);
  __syncthreads();
  if ((j & 63) == 0) l2[j >> 6] = y2v;
  __syncthreads();
  if (j == 0) outb[128] = l2[0] + l2[1];
}

// ---------------- expert GEMM + mobius pointwise -> t ----------------
__global__ __launch_bounds__(256) void k_matpre(
    const float* __restrict__ xmx, const float* __restrict__ scale,
    const float* __restrict__ xnorm, const float* __restrict__ W,
    const float* __restrict__ biasb, float* __restrict__ tout, int n, float kv, float sk,
    float maxn) {
  __shared__ float xT[64][68];
  __shared__ float Wt[64][132];
  int tid = threadIdx.x;
  int n0 = blockIdx.x * 64;
  int c = tid & 15, r = tid >> 4;

  float acc[4][8];
#pragma unroll
  for (int i = 0; i < 4; i++)
#pragma unroll
    for (int jj = 0; jj < 8; jj++) acc[i][jj] = 0.f;

  for (int kc = 0; kc < 2; kc++) {
    if (kc) __syncthreads();
#pragma unroll
    for (int it = 0; it < 32; it++) {
      int u = tid + it * 256;
      int j = u >> 6, kd = u & 63;
      Wt[kd][j] = W[j * 128 + kc * 64 + kd];
    }
#pragma unroll
    for (int it = 0; it < 4; it++) {
      int u = tid + it * 256;
      int node = u >> 4, c4 = u & 15;
      float4 v = make_float4(0.f, 0.f, 0.f, 0.f);
      if (n0 + node < n) {
        v = ((const float4*)xmx)[(size_t)(n0 + node) * 32 + kc * 16 + c4];
        if (scale) {
          float sc = scale[n0 + node];
          v.x *= sc; v.y *= sc; v.z *= sc; v.w *= sc;
        }
      }
      xT[4 * c4 + 0][node] = v.x;
      xT[4 * c4 + 1][node] = v.y;
      xT[4 * c4 + 2][node] = v.z;
      xT[4 * c4 + 3][node] = v.w;
    }
    __syncthreads();
#pragma unroll 8
    for (int kd = 0; kd < 64; kd++) {
      float4 av = *(const float4*)&xT[kd][r * 4];
      float4 b0 = *(const float4*)&Wt[kd][c * 8];
      float4 b1 = *(const float4*)&Wt[kd][c * 8 + 4];
      float a[4] = {av.x, av.y, av.z, av.w};
      float bbv[8] = {b0.x, b0.y, b0.z, b0.w, b1.x, b1.y, b1.z, b1.w};
#pragma unroll
      for (int i = 0; i < 4; i++)
#pragma unroll
        for (int jj = 0; jj < 8; jj++) acc[i][jj] = fmaf(a[i], bbv[jj], acc[i][jj]);
    }
  }

  float bp[8];
#pragma unroll
  for (int jj = 0; jj < 8; jj++) bp[jj] = biasb[c * 8 + jj];
  float y2 = biasb[128];

  float mxn2[4], sab[4], mbp[4];
#pragma unroll
  for (int i = 0; i < 4; i++) {
    float s0 = 0.f, s1 = 0.f, s2v = 0.f;
#pragma unroll
    for (int jj = 0; jj < 8; jj++) {
      float v = acc[i][jj];
      s0 = fmaf(v, v, s0);
      s1 += fabsf(v);
      s2v = fmaf(v, bp[jj], s2v);
    }
    mxn2[i] = s0;
    sab[i] = s1;
    mbp[i] = s2v;
  }
#pragma unroll
  for (int m = 1; m < 16; m <<= 1) {
#pragma unroll
    for (int i = 0; i < 4; i++) {
      mxn2[i] += __shfl_xor(mxn2[i], m, 64);
      sab[i] += __shfl_xor(sab[i], m, 64);
      mbp[i] += __shfl_xor(mbp[i], m, 64);
    }
  }

  float As[4], Cs[4];
#pragma unroll
  for (int i = 0; i < 4; i++) {
    int node = n0 + r * 4 + i;
    float xnr = xnorm[node < n ? node : (n - 1)];
    float xn = fmaxf(xnr, 1e-15f);
    float mxraw = sqrtf(mxn2[i]);
    float mxv = fmaxf(mxraw, 1e-15f);
    float ar = artan_k_d(xn, kv, sk);
    float c1 = tan_k_d(mxv / xn * ar, kv, sk);
    float s = (sab[i] == 0.f) ? 0.f : c1 / mxv;
    float pn = fmaxf(fabsf(c1) * (mxraw / mxv), 1e-15f);
    float ps = (sab[i] == 0.f) ? 1.f : proj_scale_d(pn, kv, maxn);
    s *= ps;
    float x2 = (s * s) * mxn2[i];
    float xy = s * mbp[i];
    float A = 1.f - 2.f * kv * xy - kv * y2;
    float Cc = 1.f + kv * x2;
    float den = fmaxf(1.f - 2.f * kv * xy + (kv * kv) * x2 * y2, 1e-15f);
    As[i] = A * s / den;
    Cs[i] = Cc / den;
  }

  float hb[4][8];
  float hb2[4];
#pragma unroll
  for (int i = 0; i < 4; i++) {
    float s0 = 0.f;
#pragma unroll
    for (int jj = 0; jj < 8; jj++) {
      float v = fmaf(As[i], acc[i][jj], Cs[i] * bp[jj]);
      hb[i][jj] = v;
      s0 = fmaf(v, v, s0);
    }
    hb2[i] = s0;
  }
#pragma unroll
  for (int m = 1; m < 16; m <<= 1) {
#pragma unroll
    for (int i = 0; i < 4; i++) hb2[i] += __shfl_xor(hb2[i], m, 64);
  }

#pragma unroll
  for (int i = 0; i < 4; i++) {
    int node = n0 + r * 4 + i;
    if (node >= n) continue;
    float nraw = sqrtf(hb2[i]);
    float ps2 = proj_scale_d(fmaxf(nraw, 1e-15f), kv, maxn);
    float nh = fmaxf(ps2 * nraw, 1e-15f);
    float L = artan_k_d(nh, kv, sk) / nh * ps2;
    float4 o0 = make_float4(L * hb[i][0], L * hb[i][1], L * hb[i][2], L * hb[i][3]);
    float4 o1 = make_float4(L * hb[i][4], L * hb[i][5], L * hb[i][6], L * hb[i][7]);
    float4* dst = (float4*)tout + (size_t)node * 32 + c * 2;
    dst[0] = o0;
    dst[1] = o1;
  }
}

// ---------------- edge-sweep aggregation: agg[dst] += w * t[src] ----------------
// Wave per CHUNK contiguous (dst-sorted) edges; float2 per lane; run-end
// detection via csroff (no dst array, no shuffles in the critical chain).
__global__ __launch_bounds__(256) void k_aggE(const int2* __restrict__ esw,
                                              const int* __restrict__ off,
                                              const float* __restrict__ t,
                                              float* __restrict__ agg, int etot, int n) {
  int gw = blockIdx.x * 4 + (threadIdx.x >> 6);
  int lane = threadIdx.x & 63;
  int e0 = gw * CHUNK;
  if (e0 >= etot) return;
  int e1 = min(e0 + CHUNK, etot);
  // binary search: largest cur with off[cur] <= e0
  int lo = 0, hi = n;
  while (hi - lo > 1) {
    int mid = (lo + hi) >> 1;
    if (off[mid] <= e0) lo = mid; else hi = mid;
  }
  int cur = lo;
  int eend = off[cur + 1];
  float ax = 0.f, ay = 0.f;
  int j = e0;
  for (; j + 4 <= e1; j += 4) {
    int2 m[4];
    float2 r[4];
#pragma unroll
    for (int q = 0; q < 4; q++) m[q] = esw[j + q];
#pragma unroll
    for (int q = 0; q < 4; q++) {
      int s = __builtin_amdgcn_readfirstlane(m[q].x);
      r[q] = *((const float2*)(t + (size_t)s * 128) + lane);
    }
#pragma unroll
    for (int q = 0; q < 4; q++) {
      if (j + q == eend) {
        float* dp = agg + (size_t)cur * 128 + lane * 2;
        atomicAdd(dp, ax);
        atomicAdd(dp + 1, ay);
        ax = ay = 0.f;
        cur++;
        eend = off[cur + 1];
      }
      float w = __int_as_float(m[q].y);
      ax = fmaf(w, r[q].x, ax);
      ay = fmaf(w, r[q].y, ay);
    }
  }
  for (; j < e1; j++) {
    int2 m = esw[j];
    int s = __builtin_amdgcn_readfirstlane(m.x);
    float2 rv = *((const float2*)(t + (size_t)s * 128) + lane);
    if (j == eend) {
      float* dp = agg + (size_t)cur * 128 + lane * 2;
      atomicAdd(dp, ax);
      atomicAdd(dp + 1, ay);
      ax = ay = 0.f;
      cur++;
      eend = off[cur + 1];
    }
    float w = __int_as_float(m.y);
    ax = fmaf(w, rv.x, ax);
    ay = fmaf(w, rv.y, ay);
  }
  float* dp = agg + (size_t)cur * 128 + lane * 2;
  atomicAdd(dp, ax);
  atomicAdd(dp + 1, ay);
}

// ---------------- post-agg: per-node expmap0 scale (feeds k_matpre's scale path) ----------------
__global__ void k_postnorm(const float* __restrict__ agg, float* __restrict__ scl,
                           float* __restrict__ xnk, int n, float kv, float sk, float maxn) {
  int wid = blockIdx.x * 4 + (threadIdx.x >> 6);
  int lane = threadIdx.x & 63;
  if (wid >= n) return;
  float2 v = ((const float2*)agg)[(size_t)wid * 64 + lane];
  float n2 = wsum64(fmaf(v.x, v.x, v.y * v.y));
  float nraw = sqrtf(n2);
  float nnv = fmaxf(nraw, 1e-15f);
  float tk = tan_k_d(nnv, kv, sk);
  float s = tk / nnv;
  float pn = fmaxf(fabsf(tk) * (nraw / nnv), 1e-15f);
  float ps = proj_scale_d(pn, kv, maxn);
  if (lane == 0) {
    scl[wid] = s * ps;
    xnk[wid] = pn * ps;
  }
}

// ---------------- post-agg: expmap0 + logmap0 + batch pooling -> feats ----------------
__global__ void k_postpool(const float* __restrict__ agg, const int* __restrict__ batch,
                           float* __restrict__ feats, int ex, int n, float kv, float sk,
                           float maxn) {
  int wid = blockIdx.x * 4 + (threadIdx.x >> 6);
  int lane = threadIdx.x & 63;
  if (wid >= n) return;
  float2 v = ((const float2*)agg)[(size_t)wid * 64 + lane];
  float n2 = wsum64(fmaf(v.x, v.x, v.y * v.y));
  float nraw = sqrtf(n2);
  float nnv = fmaxf(nraw, 1e-15f);
  float tk = tan_k_d(nnv, kv, sk);
  float s = tk / nnv;
  float pn = fmaxf(fabsf(tk) * (nraw / nnv), 1e-15f);
  float ps = proj_scale_d(pn, kv, maxn);
  s *= ps;
  float nh = fmaxf(pn * ps, 1e-15f);
  float sc = artan_k_d(nh, kv, sk) / nh * s;
  int b = batch[wid];
  float* dst = &feats[(size_t)b * 512 + ex * 128 + 2 * lane];
  atomicAdd(dst, sc * v.x);
  atomicAdd(dst + 1, sc * v.y);
}

// ---------------- post-agg: bias + relu + batch pooling -> hgate ----------------
__global__ void k_postgate(const float* __restrict__ agg, const float* __restrict__ bias,
                           const int* __restrict__ batch, float* __restrict__ hgate, int n) {
  int wid = blockIdx.x * 4 + (threadIdx.x >> 6);
  int lane = threadIdx.x & 63;
  if (wid >= n) return;
  float2 v = ((const float2*)agg)[(size_t)wid * 64 + lane];
  float2 bb = ((const float2*)bias)[lane];
  int b = batch[wid];
  float* dst = &hgate[(size_t)b * 128 + 2 * lane];
  atomicAdd(dst, fmaxf(v.x + bb.x, 0.f));
  atomicAdd(dst + 1, fmaxf(v.y + bb.y, 0.f));
}

// ---------------- gate GEMM 1: m1 = x @ gw1.T  [N,128] -> [N,32] ----------------
__global__ __launch_bounds__(256) void k_gate1(const float* __restrict__ x,
                                               const float* __restrict__ gw1,
                                               float* __restrict__ m1, int n) {
  __shared__ float xT[64][68];
  __shared__ float Wt[64][36];
  int tid = threadIdx.x;
  int n0 = blockIdx.x * 64;
  int c = tid & 7, r = tid >> 3;
  float acc[2][4];
#pragma unroll
  for (int i = 0; i < 2; i++)
#pragma unroll
    for (int jj = 0; jj < 4; jj++) acc[i][jj] = 0.f;

  for (int kc = 0; kc < 2; kc++) {
    if (kc) __syncthreads();
#pragma unroll
    for (int it = 0; it < 8; it++) {
      int u = tid + it * 256;
      int j = u >> 6, kd = u & 63;
      Wt[kd][j] = gw1[j * 128 + kc * 64 + kd];
    }
#pragma unroll
    for (int it = 0; it < 4; it++) {
      int u = tid + it * 256;
      int node = u >> 4, c4 = u & 15;
      float4 v = make_float4(0.f, 0.f, 0.f, 0.f);
      if (n0 + node < n) v = ((const float4*)x)[(size_t)(n0 + node) * 32 + kc * 16 + c4];
      xT[4 * c4 + 0][node] = v.x;
      xT[4 * c4 + 1][node] = v.y;
      xT[4 * c4 + 2][node] = v.z;
      xT[4 * c4 + 3][node] = v.w;
    }
    __syncthreads();
#pragma unroll 8
    for (int kd = 0; kd < 64; kd++) {
      float2 av = *(const float2*)&xT[kd][r * 2];
      float4 bv = *(const float4*)&Wt[kd][c * 4];
      float a[2] = {av.x, av.y};
      float bbv[4] = {bv.x, bv.y, bv.z, bv.w};
#pragma unroll
      for (int i = 0; i < 2; i++)
#pragma unroll
        for (int jj = 0; jj < 4; jj++) acc[i][jj] = fmaf(a[i], bbv[jj], acc[i][jj]);
    }
  }
#pragma unroll
  for (int i = 0; i < 2; i++) {
    int node = n0 + r * 2 + i;
    if (node >= n) continue;
    ((float4*)m1)[(size_t)node * 8 + c] = make_float4(acc[i][0], acc[i][1], acc[i][2], acc[i][3]);
  }
}

// ---------------- gate GEMM 2: m2 = g1 @ gw2.T  [N,32] -> [N,128] ----------------
__global__ __launch_bounds__(256) void k_gate2(const float* __restrict__ g1,
                                               const float* __restrict__ gw2,
                                               float* __restrict__ m2, int n) {
  __shared__ float xT[32][68];
  __shared__ float Wt[32][132];
  int tid = threadIdx.x;
  int n0 = blockIdx.x * 64;
  int c = tid & 15, r = tid >> 4;
  float acc[4][8];
#pragma unroll
  for (int i = 0; i < 4; i++)
#pragma unroll
    for (int jj = 0; jj < 8; jj++) acc[i][jj] = 0.f;

#pragma unroll
  for (int it = 0; it < 16; it++) {
    int u = tid + it * 256;
    int j = u >> 5, kd = u & 31;
    Wt[kd][j] = gw2[j * 32 + kd];
  }
#pragma unroll
  for (int it = 0; it < 2; it++) {
    int u = tid + it * 256;
    int node = u >> 3, c4 = u & 7;
    float4 v = make_float4(0.f, 0.f, 0.f, 0.f);
    if (n0 + node < n) v = ((const float4*)g1)[(size_t)(n0 + node) * 8 + c4];
    xT[4 * c4 + 0][node] = v.x;
    xT[4 * c4 + 1][node] = v.y;
    xT[4 * c4 + 2][node] = v.z;
    xT[4 * c4 + 3][node] = v.w;
  }
  __syncthreads();
#pragma unroll 8
  for (int kd = 0; kd < 32; kd++) {
    float4 av = *(const float4*)&xT[kd][r * 4];
    float4 b0 = *(const float4*)&Wt[kd][c * 8];
    float4 b1 = *(const float4*)&Wt[kd][c * 8 + 4];
    float a[4] = {av.x, av.y, av.z, av.w};
    float bbv[8] = {b0.x, b0.y, b0.z, b0.w, b1.x, b1.y, b1.z, b1.w};
#pragma unroll
    for (int i = 0; i < 4; i++)
#pragma unroll
      for (int jj = 0; jj < 8; jj++) acc[i][jj] = fmaf(a[i], bbv[jj], acc[i][jj]);
  }
#pragma unroll
  for (int i = 0; i < 4; i++) {
    int node = n0 + r * 4 + i;
    if (node >= n) continue;
    float4* dst = (float4*)m2 + (size_t)node * 32 + c * 2;
    dst[0] = make_float4(acc[i][0], acc[i][1], acc[i][2], acc[i][3]);
    dst[1] = make_float4(acc[i][4], acc[i][5], acc[i][6], acc[i][7]);
  }
}

// ---------------- gate aggregation dim32 + bias + relu (node-parallel) ----------------
__global__ void k_agg_relu32(const float* __restrict__ m1, const int* __restrict__ off,
                             const int2* __restrict__ esw, const float* __restrict__ bias,
                             float* __restrict__ g1, int n) {
  int node = blockIdx.x * 4 + (threadIdx.x >> 6);
  int lane = threadIdx.x & 63;
  if (node >= n) return;
  int grp = lane >> 3, l8 = lane & 7;
  int e0 = off[node], e1 = off[node + 1];
  float4 acc = make_float4(0.f, 0.f, 0.f, 0.f);
  for (int base = e0 + grp; base < e1; base += 8) {
    int2 me = esw[base];
    int ss = me.x;
    float ww = __int_as_float(me.y);
    float4 tv = ((const float4*)m1)[(size_t)ss * 8 + l8];
    acc.x = fmaf(ww, tv.x, acc.x);
    acc.y = fmaf(ww, tv.y, acc.y);
    acc.z = fmaf(ww, tv.z, acc.z);
    acc.w = fmaf(ww, tv.w, acc.w);
  }
#pragma unroll
  for (int m = 8; m <= 32; m <<= 1) {
    acc.x += __shfl_xor(acc.x, m, 64);
    acc.y += __shfl_xor(acc.y, m, 64);
    acc.z += __shfl_xor(acc.z, m, 64);
    acc.w += __shfl_xor(acc.w, m, 64);
  }
  if (grp == 0) {
    float4 bb = ((const float4*)bias)[l8];
    float4 o = make_float4(fmaxf(acc.x + bb.x, 0.f), fmaxf(acc.y + bb.y, 0.f),
                           fmaxf(acc.z + bb.z, 0.f), fmaxf(acc.w + bb.w, 0.f));
    ((float4*)g1)[(size_t)node * 8 + l8] = o;
  }
}

// ---------------- final: distance gate + softmax + outputs ----------------
__global__ __launch_bounds__(128) void k_final(const float* __restrict__ feats,
                                               const float* __restrict__ hgate,
                                               const float* __restrict__ counts,
                                               const float* __restrict__ gate_u,
                                               const float* __restrict__ tau_raw,
                                               float* __restrict__ out, CurvPack cp) {
  __shared__ float l2[2];
  int b = blockIdx.x;
  int j = threadIdx.x;
  float cnt = fmaxf(counts[b], 1.f);
  float hg = hgate[(size_t)b * 128 + j] / cnt;

  auto bsum = [&](float v) -> float {
    v = wsum64(v);
    __syncthreads();
    if ((j & 63) == 0) l2[j >> 6] = v;
    __syncthreads();
    return l2[0] + l2[1];
  };

  float nhg2 = bsum(hg * hg);
  float nhgraw = sqrtf(nhg2);
  float nhg = fmaxf(nhgraw, 1e-15f);

  float d[4], tau[4];
#pragma unroll
  for (int i = 0; i < 4; i++) {
    float kv = cp.k[i], sk = cp.sk[i], mxn = cp.mx[i];
    float tk = tan_k_d(nhg, kv, sk);
    float s = tk / nhg;
    float pn = fmaxf(fabsf(tk) * (nhgraw / nhg), 1e-15f);
    s *= proj_scale_d(pn, kv, mxn);
    float zk = s * hg;

    float u = gate_u[i * 128 + j];
    float nu2 = bsum(u * u);
    float nuraw = sqrtf(nu2);
    float nu = fmaxf(nuraw, 1e-15f);
    float tku = tan_k_d(nu, kv, sk);
    float su = tku / nu;
    float pnu = fmaxf(fabsf(tku) * (nuraw / nu), 1e-15f);
    su *= proj_scale_d(pnu, kv, mxn);
    float yk = su * u;

    float xv = -zk;
    float x2 = bsum(xv * xv);
    float y2 = bsum(yk * yk);
    float xy = bsum(xv * yk);
    float A = 1.f - 2.f * kv * xy - kv * y2;
    float C = 1.f + kv * x2;
    float den = fmaxf(1.f - 2.f * kv * xy + (kv * kv) * x2 * y2, 1e-15f);
    float ma = (A * xv + C * yk) / den;
    float m2 = bsum(ma * ma);
    float mraw = sqrtf(m2);
    float ps2 = proj_scale_d(fmaxf(mraw, 1e-15f), kv, mxn);
    float nm = fmaxf(ps2 * mraw, 1e-15f);
    d[i] = 2.f * artan_k_d(nm, kv, sk);

    float tr = tau_raw[i];
    tau[i] = fminf(fmaxf(log1pf(expf(tr)) + 0.05f, 0.05f), 10.f);
  }

  float xi[4];
  float mxv = -1e30f;
#pragma unroll
  for (int i = 0; i < 4; i++) {
    xi[i] = -d[i] / tau[i];
    mxv = fmaxf(mxv, xi[i]);
  }
  float es = 0.f, e[4];
#pragma unroll
  for (int i = 0; i < 4; i++) {
    e[i] = expf(xi[i] - mxv);
    es += e[i];
  }
  float w[4];
#pragma unroll
  for (int i = 0; i < 4; i++) w[i] = e[i] / es;

#pragma unroll
  for (int i = 0; i < 4; i++)
    out[(size_t)b * 512 + i * 128 + j] = feats[(size_t)b * 512 + i * 128 + j] / cnt * w[i];

  if (j < 4) {
    out[65536 + b * 4 + j] = w[j];
    out[66048 + b * 4 + j] = d[j];
  }
  if (b == 0 && j < 4) out[66560 + j] = tau[j];
}

// ---------------- host launcher ----------------
extern "C" void kernel_launch(void* const* d_in, const int* in_sizes, int n_in,
                              void* d_out, int out_size, void* d_ws, size_t ws_size,
                              hipStream_t stream) {
  const float* x = (const float*)d_in[0];
  const int* ei = (const int*)d_in[1];
  const int* batch = (const int*)d_in[2];
  const float* ew1 = (const float*)d_in[3];
  const float* eb1 = (const float*)d_in[4];
  const float* ew2 = (const float*)d_in[5];
  const float* eb2 = (const float*)d_in[6];
  const float* gw1 = (const float*)d_in[7];
  const float* gb1 = (const float*)d_in[8];
  const float* gw2 = (const float*)d_in[9];
  const float* gb2 = (const float*)d_in[10];
  const float* gu = (const float*)d_in[11];
  const float* traw = (const float*)d_in[12];
  float* out = (float*)d_out;

  const int N = NN, E = EE, ET = ETOT, B = BB;

  float* ws = (float*)d_ws;
  size_t o = 0;
  float* tb = ws;           o += (size_t)N * 128;
  float* agg = ws + o;      o += (size_t)N * 128;  // also m1 (=agg) / g1 (=agg+N*32)
  float* deg = ws + o;      o += N;                // becomes dinv
  float* scl1 = ws + o;     o += (size_t)4 * N;
  float* xnk1 = ws + o;     o += (size_t)4 * N;
  float* scl2 = ws + o;     o += N;
  float* xnk2 = ws + o;     o += N;
  float* counts = ws + o;   o += 256;
  float* feats = ws + o;    o += (size_t)B * 512;
  float* hg = ws + o;       o += (size_t)B * 128;
  float* biasb = ws + o;    o += 8 * 132;
  int* ideg = (int*)(ws + o);   o += N;
  int* csroff = (int*)(ws + o); o += N + 8;
  int* cursor = (int*)(ws + o); o += N;
  int2* esw = (int2*)(ws + o);  o += (size_t)2 * ET;

  float* m1 = agg;
  float* g1 = agg + (size_t)N * 32;

  // zero: counts + feats + hg (contiguous)
  hipMemsetAsync(counts, 0, (256 + (size_t)B * 512 + (size_t)B * 128) * sizeof(float), stream);

  const double curvs[4] = {-1.0, 0.0, 1.0, -0.5};
  CurvPack cp;
  for (int i = 0; i < 4; i++) {
    double kd = curvs[i];
    double skd = sqrt(fabs(kd));
    cp.k[i] = (float)kd;
    cp.sk[i] = (float)skd;
    cp.mx[i] = (kd < 0) ? (float)((1.0 - 1e-5) / skd) : 3.0e38f;
  }

  k_init<<<(N + 255) / 256, 256, 0, stream>>>(batch, deg, counts, N);
  k_deg<<<(E + 255) / 256, 256, 0, stream>>>(ei, deg, E);
  k_dinv<<<(N + 255) / 256, 256, 0, stream>>>(deg, ideg, N);
  k_scan<<<1, 1024, 0, stream>>>(ideg, csroff, cursor, N);
  k_place<<<(ET + 255) / 256, 256, 0, stream>>>(ei, deg, cursor, esw, E, N);
  k_nodeprep<<<(N + 3) / 4, 256, 0, stream>>>(x, scl1, xnk1, N, cp);
  k_biaspt_all<<<8, 128, 0, stream>>>(eb1, eb2, biasb, cp);

  const int aggBlocks = ((ET + CHUNK - 1) / CHUNK + 3) / 4;
  const size_t aggBytes = (size_t)N * 128 * sizeof(float);

  for (int ex = 0; ex < 4; ex++) {
    float kv = cp.k[ex], sk = cp.sk[ex], mxn = cp.mx[ex];
    // layer 1 (expmap0 fused via per-node scale)
    k_matpre<<<(N + 63) / 64, 256, 0, stream>>>(x, scl1 + (size_t)ex * N, xnk1 + (size_t)ex * N,
                                                ew1 + (size_t)ex * 16384, biasb + (ex * 2) * 132,
                                                tb, N, kv, sk, mxn);
    hipMemsetAsync(agg, 0, aggBytes, stream);
    k_aggE<<<aggBlocks, 256, 0, stream>>>(esw, csroff, tb, agg, ET, N);
    k_postnorm<<<(N + 3) / 4, 256, 0, stream>>>(agg, scl2, xnk2, N, kv, sk, mxn);
    // layer 2 (input = raw agg, expmap0 fused via scl2)
    k_matpre<<<(N + 63) / 64, 256, 0, stream>>>(agg, scl2, xnk2, ew2 + (size_t)ex * 16384,
                                                biasb + (ex * 2 + 1) * 132, tb, N, kv, sk, mxn);
    hipMemsetAsync(agg, 0, aggBytes, stream);
    k_aggE<<<aggBlocks, 256, 0, stream>>>(esw, csroff, tb, agg, ET, N);
    k_postpool<<<(N + 3) / 4, 256, 0, stream>>>(agg, batch, feats, ex, N, kv, sk, mxn);
  }

  // gate GCN
  k_gate1<<<(N + 63) / 64, 256, 0, stream>>>(x, gw1, m1, N);
  k_agg_relu32<<<(N + 3) / 4, 256, 0, stream>>>(m1, csroff, esw, gb1, g1, N);
  k_gate2<<<(N + 63) / 64, 256, 0, stream>>>(g1, gw2, tb, N);
  hipMemsetAsync(agg, 0, aggBytes, stream);
  k_aggE<<<aggBlocks, 256, 0, stream>>>(esw, csroff, tb, agg, ET, N);
  k_postgate<<<(N + 3) / 4, 256, 0, stream>>>(agg, gb2, batch, hg, N);

  k_final<<<B, 128, 0, stream>>>(feats, hg, counts, gu, traw, out, cp);

  (void)in_sizes; (void)n_in; (void)out_size; (void)ws_size;
}

// Round 4
// 1790.981 us; speedup vs baseline: 1.2701x; 1.2371x over previous
//
#include <hip/hip_runtime.h>
#include <math.h>

// ---------------- constants ----------------
#define NN 50000
#define EE 800000
#define ETOT (EE + NN)
#define BB 128
#define DIM 128
#define GHID 32
#define CHUNK 128
#define NCH 128

typedef _Float16 f16;
typedef _Float16 f16x2 __attribute__((ext_vector_type(2)));
typedef _Float16 f16x8 __attribute__((ext_vector_type(8)));

struct CurvPack {
  float k[4], sk[4], mx[4];
};

// ---------------- device math helpers ----------------
__device__ __forceinline__ float wsum64(float v) {
#pragma unroll
  for (int m = 32; m; m >>= 1) v += __shfl_xor(v, m, 64);
  return v;
}

__device__ __forceinline__ float tan_k_d(float x, float kv, float sk) {
  if (kv > 0.f) return tanf(x * sk) / sk;
  if (kv < 0.f) return tanhf(x * sk) / sk;
  return x;
}

__device__ __forceinline__ float artan_k_d(float x, float kv, float sk) {
  if (kv > 0.f) return atanf(x * sk) / sk;
  if (kv < 0.f) {
    float t = x * sk;
    t = fminf(fmaxf(t, -1.f + 1e-7f), 1.f - 1e-7f);
    return atanhf(t) / sk;
  }
  return x;
}

__device__ __forceinline__ float proj_scale_d(float n, float kv, float maxn) {
  if (kv < 0.f && n > maxn) return maxn / n;
  return 1.f;
}

// ---------------- graph preprocessing ----------------
__global__ void k_init(float* __restrict__ deg, int n) {
  int i = blockIdx.x * 256 + threadIdx.x;
  if (i < n) deg[i] = 1.0f;  // self loop
}

// counts + batch offsets via binary search (batch is sorted; no atomics)
__global__ void k_counts(const int* __restrict__ batch, int* __restrict__ boff,
                         float* __restrict__ counts, int n) {
  int b = threadIdx.x;  // 0..255
  if (b <= 128) {
    int lo = 0, hi = n;
    while (lo < hi) {
      int mid = (lo + hi) >> 1;
      if (batch[mid] < b) lo = mid + 1; else hi = mid;
    }
    boff[b] = lo;
  }
  __syncthreads();
  if (b < 128) counts[b] = (float)(boff[b + 1] - boff[b]);
}

__global__ void k_deg(const int* __restrict__ ei, float* __restrict__ deg, int e) {
  int i = blockIdx.x * 256 + threadIdx.x;
  if (i < e) atomicAdd(&deg[ei[e + i]], 1.0f);  // col = edge_index[1]
}

__global__ void k_dinv(float* __restrict__ deg, int* __restrict__ ideg, int n) {
  int i = blockIdx.x * 256 + threadIdx.x;
  if (i < n) {
    float d = deg[i];
    ideg[i] = (int)(d + 0.5f);
    deg[i] = 1.0f / sqrtf(d);  // deg buffer becomes dinv
  }
}

// single-block exclusive scan of ideg -> off[0..n], cursor copy
__global__ void k_scan(const int* __restrict__ ideg, int* __restrict__ off,
                       int* __restrict__ cursor, int n) {
  __shared__ int wsh[16];
  int tid = threadIdx.x;
  int lane = tid & 63;
  int w = tid >> 6;
  int carry = 0;
  for (int base = 0; base < n; base += 1024) {
    int idx = base + tid;
    int v = (idx < n) ? ideg[idx] : 0;
    int x = v;
#pragma unroll
    for (int o2 = 1; o2 < 64; o2 <<= 1) {
      int t2 = __shfl_up(x, o2, 64);
      if (lane >= o2) x += t2;
    }
    if (lane == 63) wsh[w] = x;
    __syncthreads();
    if (tid < 16) {
      int s = wsh[tid];
#pragma unroll
      for (int o2 = 1; o2 < 16; o2 <<= 1) {
        int t2 = __shfl_up(s, o2, 64);
        if (lane >= o2) s += t2;
      }
      wsh[tid] = s;
    }
    __syncthreads();
    int woff = carry + (w ? wsh[w - 1] : 0);
    int incl = woff + x;
    if (idx < n) {
      off[idx] = incl - v;
      cursor[idx] = incl - v;
    }
    carry += wsh[15];
    __syncthreads();
  }
  if (tid == 0) off[n] = carry;
}

// place edges: esw[p] = (src, weight_bits) at dst-sorted position
__global__ void k_place(const int* __restrict__ ei, const float* __restrict__ dinv,
                        int* __restrict__ cursor, int2* __restrict__ esw, int e, int n) {
  int i = blockIdx.x * 256 + threadIdx.x;
  int et = e + n;
  if (i >= et) return;
  int r_, c_;
  if (i < e) {
    r_ = ei[i];
    c_ = ei[e + i];
  } else {
    r_ = i - e;
    c_ = i - e;
  }
  int p = atomicAdd(&cursor[c_], 1);
  esw[p] = make_int2(r_, __float_as_int(dinv[r_] * dinv[c_]));
}

// ---------------- per-node prep: raw norm of x + all 4 expert expmap0 scales ----------------
__global__ void k_nodeprep(const float* __restrict__ x, float* __restrict__ scl,
                           float* __restrict__ xnk, int n, CurvPack cp) {
  int wid = blockIdx.x * 4 + (threadIdx.x >> 6);
  int lane = threadIdx.x & 63;
  if (wid >= n) return;
  float2 v = ((const float2*)x)[(size_t)wid * 64 + lane];
  float n2 = wsum64(v.x * v.x + v.y * v.y);
  float nraw = sqrtf(n2);
  if (lane < 4) {
    float kv = cp.k[lane], sk = cp.sk[lane], maxn = cp.mx[lane];
    float nnv = fmaxf(nraw, 1e-15f);
    float tk = tan_k_d(nnv, kv, sk);
    float s = tk / nnv;
    float pn = fmaxf(fabsf(tk) * (nraw / nnv), 1e-15f);
    float ps = proj_scale_d(pn, kv, maxn);
    scl[(size_t)lane * n + wid] = s * ps;
    xnk[(size_t)lane * n + wid] = pn * ps;
  }
}

// ---------------- bias points: expmap0(b) for all 8 (expert,layer) pairs ----------------
__global__ void k_biaspt_all(const float* __restrict__ eb1, const float* __restrict__ eb2,
                             float* __restrict__ biasb, CurvPack cp) {
  __shared__ float l2[2];
  int blk = blockIdx.x;  // ex*2 + layer
  int ex = blk >> 1, layer = blk & 1;
  float kv = cp.k[ex], sk = cp.sk[ex], maxn = cp.mx[ex];
  const float* b = (layer ? eb2 : eb1) + ex * 128;
  float* outb = biasb + blk * 132;
  int j = threadIdx.x;  // 0..127
  float v = b[j];
  float n2 = wsum64(v * v);
  if ((j & 63) == 0) l2[j >> 6] = n2;
  __syncthreads();
  n2 = l2[0] + l2[1];
  float nraw = sqrtf(n2);
  float nnv = fmaxf(nraw, 1e-15f);
  float tk = tan_k_d(nnv, kv, sk);
  float s = tk / nnv;
  float pn = fmaxf(fabsf(tk) * (nraw / nnv), 1e-15f);
  float ps = proj_scale_d(pn, kv, maxn);
  float bp = ps * s * v;
  outb[j] = bp;
  float y2v = wsum64(bp * bp);
  __syncthreads();
  if ((j & 63) == 0) l2[j >> 6] = y2v;
  __syncthreads();
  if (j == 0) outb[128] = l2[0] + l2[1];
}

// ---------------- expert GEMM + mobius pointwise -> t (fp16 out) ----------------
__global__ __launch_bounds__(256) void k_matpre(
    const float* __restrict__ xmx, const float* __restrict__ scale,
    const float* __restrict__ xnorm, const float* __restrict__ W,
    const float* __restrict__ biasb, f16* __restrict__ tout, int n, float kv, float sk,
    float maxn) {
  __shared__ float xT[64][68];
  __shared__ float Wt[64][132];
  int tid = threadIdx.x;
  int n0 = blockIdx.x * 64;
  int c = tid & 15, r = tid >> 4;

  float acc[4][8];
#pragma unroll
  for (int i = 0; i < 4; i++)
#pragma unroll
    for (int jj = 0; jj < 8; jj++) acc[i][jj] = 0.f;

  for (int kc = 0; kc < 2; kc++) {
    if (kc) __syncthreads();
#pragma unroll
    for (int it = 0; it < 32; it++) {
      int u = tid + it * 256;
      int j = u >> 6, kd = u & 63;
      Wt[kd][j] = W[j * 128 + kc * 64 + kd];
    }
#pragma unroll
    for (int it = 0; it < 4; it++) {
      int u = tid + it * 256;
      int node = u >> 4, c4 = u & 15;
      float4 v = make_float4(0.f, 0.f, 0.f, 0.f);
      if (n0 + node < n) {
        v = ((const float4*)xmx)[(size_t)(n0 + node) * 32 + kc * 16 + c4];
        if (scale) {
          float sc = scale[n0 + node];
          v.x *= sc; v.y *= sc; v.z *= sc; v.w *= sc;
        }
      }
      xT[4 * c4 + 0][node] = v.x;
      xT[4 * c4 + 1][node] = v.y;
      xT[4 * c4 + 2][node] = v.z;
      xT[4 * c4 + 3][node] = v.w;
    }
    __syncthreads();
#pragma unroll 8
    for (int kd = 0; kd < 64; kd++) {
      float4 av = *(const float4*)&xT[kd][r * 4];
      float4 b0 = *(const float4*)&Wt[kd][c * 8];
      float4 b1 = *(const float4*)&Wt[kd][c * 8 + 4];
      float a[4] = {av.x, av.y, av.z, av.w};
      float bbv[8] = {b0.x, b0.y, b0.z, b0.w, b1.x, b1.y, b1.z, b1.w};
#pragma unroll
      for (int i = 0; i < 4; i++)
#pragma unroll
        for (int jj = 0; jj < 8; jj++) acc[i][jj] = fmaf(a[i], bbv[jj], acc[i][jj]);
    }
  }

  float bp[8];
#pragma unroll
  for (int jj = 0; jj < 8; jj++) bp[jj] = biasb[c * 8 + jj];
  float y2 = biasb[128];

  float mxn2[4], sab[4], mbp[4];
#pragma unroll
  for (int i = 0; i < 4; i++) {
    float s0 = 0.f, s1 = 0.f, s2v = 0.f;
#pragma unroll
    for (int jj = 0; jj < 8; jj++) {
      float v = acc[i][jj];
      s0 = fmaf(v, v, s0);
      s1 += fabsf(v);
      s2v = fmaf(v, bp[jj], s2v);
    }
    mxn2[i] = s0;
    sab[i] = s1;
    mbp[i] = s2v;
  }
#pragma unroll
  for (int m = 1; m < 16; m <<= 1) {
#pragma unroll
    for (int i = 0; i < 4; i++) {
      mxn2[i] += __shfl_xor(mxn2[i], m, 64);
      sab[i] += __shfl_xor(sab[i], m, 64);
      mbp[i] += __shfl_xor(mbp[i], m, 64);
    }
  }

  float As[4], Cs[4];
#pragma unroll
  for (int i = 0; i < 4; i++) {
    int node = n0 + r * 4 + i;
    float xnr = xnorm[node < n ? node : (n - 1)];
    float xn = fmaxf(xnr, 1e-15f);
    float mxraw = sqrtf(mxn2[i]);
    float mxv = fmaxf(mxraw, 1e-15f);
    float ar = artan_k_d(xn, kv, sk);
    float c1 = tan_k_d(mxv / xn * ar, kv, sk);
    float s = (sab[i] == 0.f) ? 0.f : c1 / mxv;
    float pn = fmaxf(fabsf(c1) * (mxraw / mxv), 1e-15f);
    float ps = (sab[i] == 0.f) ? 1.f : proj_scale_d(pn, kv, maxn);
    s *= ps;
    float x2 = (s * s) * mxn2[i];
    float xy = s * mbp[i];
    float A = 1.f - 2.f * kv * xy - kv * y2;
    float Cc = 1.f + kv * x2;
    float den = fmaxf(1.f - 2.f * kv * xy + (kv * kv) * x2 * y2, 1e-15f);
    As[i] = A * s / den;
    Cs[i] = Cc / den;
  }

  float hb[4][8];
  float hb2[4];
#pragma unroll
  for (int i = 0; i < 4; i++) {
    float s0 = 0.f;
#pragma unroll
    for (int jj = 0; jj < 8; jj++) {
      float v = fmaf(As[i], acc[i][jj], Cs[i] * bp[jj]);
      hb[i][jj] = v;
      s0 = fmaf(v, v, s0);
    }
    hb2[i] = s0;
  }
#pragma unroll
  for (int m = 1; m < 16; m <<= 1) {
#pragma unroll
    for (int i = 0; i < 4; i++) hb2[i] += __shfl_xor(hb2[i], m, 64);
  }

#pragma unroll
  for (int i = 0; i < 4; i++) {
    int node = n0 + r * 4 + i;
    if (node >= n) continue;
    float nraw = sqrtf(hb2[i]);
    float ps2 = proj_scale_d(fmaxf(nraw, 1e-15f), kv, maxn);
    float nh = fmaxf(ps2 * nraw, 1e-15f);
    float L = artan_k_d(nh, kv, sk) / nh * ps2;
    f16x8 hv;
#pragma unroll
    for (int jj = 0; jj < 8; jj++) hv[jj] = (f16)(L * hb[i][jj]);
    *((f16x8*)(tout + (size_t)node * 128) + c) = hv;
  }
}

// ---------------- edge-sweep aggregation: agg[dst] += w * t[src] (fp16 rows) ----------------
__global__ __launch_bounds__(256) void k_aggE(const int2* __restrict__ esw,
                                              const int* __restrict__ off,
                                              const f16x2* __restrict__ t,
                                              float* __restrict__ agg, int etot, int n) {
  int gw = blockIdx.x * 4 + (threadIdx.x >> 6);
  int lane = threadIdx.x & 63;
  int e0 = gw * CHUNK;
  if (e0 >= etot) return;
  int e1 = min(e0 + CHUNK, etot);
  // binary search: largest cur with off[cur] <= e0
  int lo = 0, hi = n;
  while (hi - lo > 1) {
    int mid = (lo + hi) >> 1;
    if (off[mid] <= e0) lo = mid; else hi = mid;
  }
  int cur = lo;
  int runStart = off[cur];
  int eend = off[cur + 1];
  float ax = 0.f, ay = 0.f;
  int j = e0;
  while (j < e1) {
    if (j + 8 <= e1 && eend >= j + 8) {
      int2 m[8];
#pragma unroll
      for (int q = 0; q < 8; q++) m[q] = esw[j + q];
      f16x2 r[8];
#pragma unroll
      for (int q = 0; q < 8; q++) {
        int s = __builtin_amdgcn_readfirstlane(m[q].x);
        r[q] = t[(size_t)s * 64 + lane];
      }
#pragma unroll
      for (int q = 0; q < 8; q++) {
        float w = __int_as_float(m[q].y);
        ax = fmaf(w, (float)r[q][0], ax);
        ay = fmaf(w, (float)r[q][1], ay);
      }
      j += 8;
    } else if (j + 4 <= e1 && eend >= j + 4) {
      int2 m[4];
#pragma unroll
      for (int q = 0; q < 4; q++) m[q] = esw[j + q];
      f16x2 r[4];
#pragma unroll
      for (int q = 0; q < 4; q++) {
        int s = __builtin_amdgcn_readfirstlane(m[q].x);
        r[q] = t[(size_t)s * 64 + lane];
      }
#pragma unroll
      for (int q = 0; q < 4; q++) {
        float w = __int_as_float(m[q].y);
        ax = fmaf(w, (float)r[q][0], ax);
        ay = fmaf(w, (float)r[q][1], ay);
      }
      j += 4;
    } else {
      if (j == eend) {
        float* dp = agg + (size_t)cur * 128 + lane * 2;
        if (runStart >= e0) {
          dp[0] = ax;
          dp[1] = ay;
        } else {
          atomicAdd(dp, ax);
          atomicAdd(dp + 1, ay);
        }
        ax = ay = 0.f;
        runStart = j;
        cur++;
        eend = off[cur + 1];
      }
      int2 m = esw[j];
      int s = __builtin_amdgcn_readfirstlane(m.x);
      f16x2 rv = t[(size_t)s * 64 + lane];
      float w = __int_as_float(m.y);
      ax = fmaf(w, (float)rv[0], ax);
      ay = fmaf(w, (float)rv[1], ay);
      j++;
    }
  }
  float* dp = agg + (size_t)cur * 128 + lane * 2;
  if (runStart >= e0 && eend <= e1) {
    dp[0] = ax;
    dp[1] = ay;
  } else {
    atomicAdd(dp, ax);
    atomicAdd(dp + 1, ay);
  }
}

// ---------------- post-agg: per-node expmap0 scale ----------------
__global__ void k_postnorm(const float* __restrict__ agg, float* __restrict__ scl,
                           float* __restrict__ xnk, int n, float kv, float sk, float maxn) {
  int wid = blockIdx.x * 4 + (threadIdx.x >> 6);
  int lane = threadIdx.x & 63;
  if (wid >= n) return;
  float2 v = ((const float2*)agg)[(size_t)wid * 64 + lane];
  float n2 = wsum64(fmaf(v.x, v.x, v.y * v.y));
  float nraw = sqrtf(n2);
  float nnv = fmaxf(nraw, 1e-15f);
  float tk = tan_k_d(nnv, kv, sk);
  float s = tk / nnv;
  float pn = fmaxf(fabsf(tk) * (nraw / nnv), 1e-15f);
  float ps = proj_scale_d(pn, kv, maxn);
  if (lane == 0) {
    scl[wid] = s * ps;
    xnk[wid] = pn * ps;
  }
}

// ---------------- node-strip batch pooling: expmap0+logmap0 -> feats ----------------
__global__ void k_postpool(const float* __restrict__ agg, const int* __restrict__ boff,
                           float* __restrict__ feats, int ex, int n, float kv, float sk,
                           float maxn) {
  int gw = blockIdx.x * 4 + (threadIdx.x >> 6);
  int lane = threadIdx.x & 63;
  int n0 = gw * NCH;
  if (n0 >= n) return;
  int n1 = min(n0 + NCH, n);
  int lo = 0, hi = 128;
  while (hi - lo > 1) {
    int mid = (lo + hi) >> 1;
    if (boff[mid] <= n0) lo = mid; else hi = mid;
  }
  int cb = lo;
  int runStart = boff[cb];
  int bend = boff[cb + 1];
  float ax = 0.f, ay = 0.f;
  for (int node = n0; node < n1; node++) {
    while (node == bend) {
      float* dp = &feats[(size_t)cb * 512 + ex * 128 + lane * 2];
      if (runStart >= n0) {
        dp[0] = ax;
        dp[1] = ay;
      } else {
        atomicAdd(dp, ax);
        atomicAdd(dp + 1, ay);
      }
      ax = ay = 0.f;
      runStart = node;
      cb++;
      bend = boff[cb + 1];
    }
    float2 v = ((const float2*)agg)[(size_t)node * 64 + lane];
    float n2 = wsum64(fmaf(v.x, v.x, v.y * v.y));
    float nraw = sqrtf(n2);
    float nnv = fmaxf(nraw, 1e-15f);
    float tk = tan_k_d(nnv, kv, sk);
    float s = tk / nnv;
    float pn = fmaxf(fabsf(tk) * (nraw / nnv), 1e-15f);
    float ps = proj_scale_d(pn, kv, maxn);
    s *= ps;
    float nh = fmaxf(pn * ps, 1e-15f);
    float sc = artan_k_d(nh, kv, sk) / nh * s;
    ax = fmaf(sc, v.x, ax);
    ay = fmaf(sc, v.y, ay);
  }
  float* dp = &feats[(size_t)cb * 512 + ex * 128 + lane * 2];
  if (runStart >= n0 && bend <= n1) {
    dp[0] = ax;
    dp[1] = ay;
  } else {
    atomicAdd(dp, ax);
    atomicAdd(dp + 1, ay);
  }
}

// ---------------- node-strip gate pooling: bias+relu -> hgate ----------------
__global__ void k_postgate(const float* __restrict__ agg, const int* __restrict__ boff,
                           const float* __restrict__ bias, float* __restrict__ hgate, int n) {
  int gw = blockIdx.x * 4 + (threadIdx.x >> 6);
  int lane = threadIdx.x & 63;
  int n0 = gw * NCH;
  if (n0 >= n) return;
  int n1 = min(n0 + NCH, n);
  int lo = 0, hi = 128;
  while (hi - lo > 1) {
    int mid = (lo + hi) >> 1;
    if (boff[mid] <= n0) lo = mid; else hi = mid;
  }
  int cb = lo;
  int runStart = boff[cb];
  int bend = boff[cb + 1];
  float2 bb = ((const float2*)bias)[lane];
  float ax = 0.f, ay = 0.f;
  for (int node = n0; node < n1; node++) {
    while (node == bend) {
      float* dp = &hgate[(size_t)cb * 128 + lane * 2];
      if (runStart >= n0) {
        dp[0] = ax;
        dp[1] = ay;
      } else {
        atomicAdd(dp, ax);
        atomicAdd(dp + 1, ay);
      }
      ax = ay = 0.f;
      runStart = node;
      cb++;
      bend = boff[cb + 1];
    }
    float2 v = ((const float2*)agg)[(size_t)node * 64 + lane];
    ax += fmaxf(v.x + bb.x, 0.f);
    ay += fmaxf(v.y + bb.y, 0.f);
  }
  float* dp = &hgate[(size_t)cb * 128 + lane * 2];
  if (runStart >= n0 && bend <= n1) {
    dp[0] = ax;
    dp[1] = ay;
  } else {
    atomicAdd(dp, ax);
    atomicAdd(dp + 1, ay);
  }
}

// ---------------- gate GEMM 1: m1 = x @ gw1.T  [N,128] -> [N,32] ----------------
__global__ __launch_bounds__(256) void k_gate1(const float* __restrict__ x,
                                               const float* __restrict__ gw1,
                                               float* __restrict__ m1, int n) {
  __shared__ float xT[64][68];
  __shared__ float Wt[64][36];
  int tid = threadIdx.x;
  int n0 = blockIdx.x * 64;
  int c = tid & 7, r = tid >> 3;
  float acc[2][4];
#pragma unroll
  for (int i = 0; i < 2; i++)
#pragma unroll
    for (int jj = 0; jj < 4; jj++) acc[i][jj] = 0.f;

  for (int kc = 0; kc < 2; kc++) {
    if (kc) __syncthreads();
#pragma unroll
    for (int it = 0; it < 8; it++) {
      int u = tid + it * 256;
      int j = u >> 6, kd = u & 63;
      Wt[kd][j] = gw1[j * 128 + kc * 64 + kd];
    }
#pragma unroll
    for (int it = 0; it < 4; it++) {
      int u = tid + it * 256;
      int node = u >> 4, c4 = u & 15;
      float4 v = make_float4(0.f, 0.f, 0.f, 0.f);
      if (n0 + node < n) v = ((const float4*)x)[(size_t)(n0 + node) * 32 + kc * 16 + c4];
      xT[4 * c4 + 0][node] = v.x;
      xT[4 * c4 + 1][node] = v.y;
      xT[4 * c4 + 2][node] = v.z;
      xT[4 * c4 + 3][node] = v.w;
    }
    __syncthreads();
#pragma unroll 8
    for (int kd = 0; kd < 64; kd++) {
      float2 av = *(const float2*)&xT[kd][r * 2];
      float4 bv = *(const float4*)&Wt[kd][c * 4];
      float a[2] = {av.x, av.y};
      float bbv[4] = {bv.x, bv.y, bv.z, bv.w};
#pragma unroll
      for (int i = 0; i < 2; i++)
#pragma unroll
        for (int jj = 0; jj < 4; jj++) acc[i][jj] = fmaf(a[i], bbv[jj], acc[i][jj]);
    }
  }
#pragma unroll
  for (int i = 0; i < 2; i++) {
    int node = n0 + r * 2 + i;
    if (node >= n) continue;
    ((float4*)m1)[(size_t)node * 8 + c] = make_float4(acc[i][0], acc[i][1], acc[i][2], acc[i][3]);
  }
}

// ---------------- gate GEMM 2: m2 = g1 @ gw2.T  [N,32] -> [N,128] fp16 out ----------------
__global__ __launch_bounds__(256) void k_gate2(const float* __restrict__ g1,
                                               const float* __restrict__ gw2,
                                               f16* __restrict__ m2, int n) {
  __shared__ float xT[32][68];
  __shared__ float Wt[32][132];
  int tid = threadIdx.x;
  int n0 = blockIdx.x * 64;
  int c = tid & 15, r = tid >> 4;
  float acc[4][8];
#pragma unroll
  for (int i = 0; i < 4; i++)
#pragma unroll
    for (int jj = 0; jj < 8; jj++) acc[i][jj] = 0.f;

#pragma unroll
  for (int it = 0; it < 16; it++) {
    int u = tid + it * 256;
    int j = u >> 5, kd = u & 31;
    Wt[kd][j] = gw2[j * 32 + kd];
  }
#pragma unroll
  for (int it = 0; it < 2; it++) {
    int u = tid + it * 256;
    int node = u >> 3, c4 = u & 7;
    float4 v = make_float4(0.f, 0.f, 0.f, 0.f);
    if (n0 + node < n) v = ((const float4*)g1)[(size_t)(n0 + node) * 8 + c4];
    xT[4 * c4 + 0][node] = v.x;
    xT[4 * c4 + 1][node] = v.y;
    xT[4 * c4 + 2][node] = v.z;
    xT[4 * c4 + 3][node] = v.w;
  }
  __syncthreads();
#pragma unroll 8
  for (int kd = 0; kd < 32; kd++) {
    float4 av = *(const float4*)&xT[kd][r * 4];
    float4 b0 = *(const float4*)&Wt[kd][c * 8];
    float4 b1 = *(const float4*)&Wt[kd][c * 8 + 4];
    float a[4] = {av.x, av.y, av.z, av.w};
    float bbv[8] = {b0.x, b0.y, b0.z, b0.w, b1.x, b1.y, b1.z, b1.w};
#pragma unroll
    for (int i = 0; i < 4; i++)
#pragma unroll
      for (int jj = 0; jj < 8; jj++) acc[i][jj] = fmaf(a[i], bbv[jj], acc[i][jj]);
  }
#pragma unroll
  for (int i = 0; i < 4; i++) {
    int node = n0 + r * 4 + i;
    if (node >= n) continue;
    f16x8 hv;
#pragma unroll
    for (int jj = 0; jj < 8; jj++) hv[jj] = (f16)acc[i][jj];
    *((f16x8*)(m2 + (size_t)node * 128) + c) = hv;
  }
}

// ---------------- gate aggregation dim32 + bias + relu (node-parallel) ----------------
__global__ void k_agg_relu32(const float* __restrict__ m1, const int* __restrict__ off,
                             const int2* __restrict__ esw, const float* __restrict__ bias,
                             float* __restrict__ g1, int n) {
  int node = blockIdx.x * 4 + (threadIdx.x >> 6);
  int lane = threadIdx.x & 63;
  if (node >= n) return;
  int grp = lane >> 3, l8 = lane & 7;
  int e0 = off[node], e1 = off[node + 1];
  float4 acc = make_float4(0.f, 0.f, 0.f, 0.f);
  for (int base = e0 + grp; base < e1; base += 8) {
    int2 me = esw[base];
    int ss = me.x;
    float ww = __int_as_float(me.y);
    float4 tv = ((const float4*)m1)[(size_t)ss * 8 + l8];
    acc.x = fmaf(ww, tv.x, acc.x);
    acc.y = fmaf(ww, tv.y, acc.y);
    acc.z = fmaf(ww, tv.z, acc.z);
    acc.w = fmaf(ww, tv.w, acc.w);
  }
#pragma unroll
  for (int m = 8; m <= 32; m <<= 1) {
    acc.x += __shfl_xor(acc.x, m, 64);
    acc.y += __shfl_xor(acc.y, m, 64);
    acc.z += __shfl_xor(acc.z, m, 64);
    acc.w += __shfl_xor(acc.w, m, 64);
  }
  if (grp == 0) {
    float4 bb = ((const float4*)bias)[l8];
    float4 o = make_float4(fmaxf(acc.x + bb.x, 0.f), fmaxf(acc.y + bb.y, 0.f),
                           fmaxf(acc.z + bb.z, 0.f), fmaxf(acc.w + bb.w, 0.f));
    ((float4*)g1)[(size_t)node * 8 + l8] = o;
  }
}

// ---------------- final: distance gate + softmax + outputs ----------------
__global__ __launch_bounds__(128) void k_final(const float* __restrict__ feats,
                                               const float* __restrict__ hgate,
                                               const float* __restrict__ counts,
                                               const float* __restrict__ gate_u,
                                               const float* __restrict__ tau_raw,
                                               float* __restrict__ out, CurvPack cp) {
  __shared__ float l2[2];
  int b = blockIdx.x;
  int j = threadIdx.x;
  float cnt = fmaxf(counts[b], 1.f);
  float hg = hgate[(size_t)b * 128 + j] / cnt;

  auto bsum = [&](float v) -> float {
    v = wsum64(v);
    __syncthreads();
    if ((j & 63) == 0) l2[j >> 6] = v;
    __syncthreads();
    return l2[0] + l2[1];
  };

  float nhg2 = bsum(hg * hg);
  float nhgraw = sqrtf(nhg2);
  float nhg = fmaxf(nhgraw, 1e-15f);

  float d[4], tau[4];
#pragma unroll
  for (int i = 0; i < 4; i++) {
    float kv = cp.k[i], sk = cp.sk[i], mxn = cp.mx[i];
    float tk = tan_k_d(nhg, kv, sk);
    float s = tk / nhg;
    float pn = fmaxf(fabsf(tk) * (nhgraw / nhg), 1e-15f);
    s *= proj_scale_d(pn, kv, mxn);
    float zk = s * hg;

    float u = gate_u[i * 128 + j];
    float nu2 = bsum(u * u);
    float nuraw = sqrtf(nu2);
    float nu = fmaxf(nuraw, 1e-15f);
    float tku = tan_k_d(nu, kv, sk);
    float su = tku / nu;
    float pnu = fmaxf(fabsf(tku) * (nuraw / nu), 1e-15f);
    su *= proj_scale_d(pnu, kv, mxn);
    float yk = su * u;

    float xv = -zk;
    float x2 = bsum(xv * xv);
    float y2 = bsum(yk * yk);
    float xy = bsum(xv * yk);
    float A = 1.f - 2.f * kv * xy - kv * y2;
    float C = 1.f + kv * x2;
    float den = fmaxf(1.f - 2.f * kv * xy + (kv * kv) * x2 * y2, 1e-15f);
    float ma = (A * xv + C * yk) / den;
    float m2 = bsum(ma * ma);
    float mraw = sqrtf(m2);
    float ps2 = proj_scale_d(fmaxf(mraw, 1e-15f), kv, mxn);
    float nm = fmaxf(ps2 * mraw, 1e-15f);
    d[i] = 2.f * artan_k_d(nm, kv, sk);

    float tr = tau_raw[i];
    tau[i] = fminf(fmaxf(log1pf(expf(tr)) + 0.05f, 0.05f), 10.f);
  }

  float xi[4];
  float mxv = -1e30f;
#pragma unroll
  for (int i = 0; i < 4; i++) {
    xi[i] = -d[i] / tau[i];
    mxv = fmaxf(mxv, xi[i]);
  }
  float es = 0.f, e[4];
#pragma unroll
  for (int i = 0; i < 4; i++) {
    e[i] = expf(xi[i] - mxv);
    es += e[i];
  }
  float w[4];
#pragma unroll
  for (int i = 0; i < 4; i++) w[i] = e[i] / es;

#pragma unroll
  for (int i = 0; i < 4; i++)
    out[(size_t)b * 512 + i * 128 + j] = feats[(size_t)b * 512 + i * 128 + j] / cnt * w[i];

  if (j < 4) {
    out[65536 + b * 4 + j] = w[j];
    out[66048 + b * 4 + j] = d[j];
  }
  if (b == 0 && j < 4) out[66560 + j] = tau[j];
}

// ---------------- host launcher ----------------
extern "C" void kernel_launch(void* const* d_in, const int* in_sizes, int n_in,
                              void* d_out, int out_size, void* d_ws, size_t ws_size,
                              hipStream_t stream) {
  const float* x = (const float*)d_in[0];
  const int* ei = (const int*)d_in[1];
  const int* batch = (const int*)d_in[2];
  const float* ew1 = (const float*)d_in[3];
  const float* eb1 = (const float*)d_in[4];
  const float* ew2 = (const float*)d_in[5];
  const float* eb2 = (const float*)d_in[6];
  const float* gw1 = (const float*)d_in[7];
  const float* gb1 = (const float*)d_in[8];
  const float* gw2 = (const float*)d_in[9];
  const float* gb2 = (const float*)d_in[10];
  const float* gu = (const float*)d_in[11];
  const float* traw = (const float*)d_in[12];
  float* out = (float*)d_out;

  const int N = NN, E = EE, ET = ETOT, B = BB;

  float* ws = (float*)d_ws;
  size_t o = 0;
  f16* tbh = (f16*)ws;      o += (size_t)N * 64;  // N*128 halfs (16B-aligned)
  float* agg = ws + o;      o += (size_t)N * 128;
  float* m1 = ws + o;       o += (size_t)N * 32;
  float* g1 = ws + o;       o += (size_t)N * 32;
  float* deg = ws + o;      o += N;  // becomes dinv
  float* scl1 = ws + o;     o += (size_t)4 * N;
  float* xnk1 = ws + o;     o += (size_t)4 * N;
  float* scl2 = ws + o;     o += N;
  float* xnk2 = ws + o;     o += N;
  float* counts = ws + o;   o += 256;
  float* feats = ws + o;    o += (size_t)B * 512;
  float* hg = ws + o;       o += (size_t)B * 128;
  float* biasb = ws + o;    o += 8 * 132;
  int* ideg = (int*)(ws + o);   o += N;
  int* csroff = (int*)(ws + o); o += N + 8;
  int* cursor = (int*)(ws + o); o += N;
  int* boff = (int*)(ws + o);   o += 136;
  int2* esw = (int2*)(ws + o);  o += (size_t)2 * ET;

  // zero: counts + feats + hg (contiguous)
  hipMemsetAsync(counts, 0, (256 + (size_t)B * 512 + (size_t)B * 128) * sizeof(float), stream);

  const double curvs[4] = {-1.0, 0.0, 1.0, -0.5};
  CurvPack cp;
  for (int i = 0; i < 4; i++) {
    double kd = curvs[i];
    double skd = sqrt(fabs(kd));
    cp.k[i] = (float)kd;
    cp.sk[i] = (float)skd;
    cp.mx[i] = (kd < 0) ? (float)((1.0 - 1e-5) / skd) : 3.0e38f;
  }

  k_init<<<(N + 255) / 256, 256, 0, stream>>>(deg, N);
  k_counts<<<1, 256, 0, stream>>>(batch, boff, counts, N);
  k_deg<<<(E + 255) / 256, 256, 0, stream>>>(ei, deg, E);
  k_dinv<<<(N + 255) / 256, 256, 0, stream>>>(deg, ideg, N);
  k_scan<<<1, 1024, 0, stream>>>(ideg, csroff, cursor, N);
  k_place<<<(ET + 255) / 256, 256, 0, stream>>>(ei, deg, cursor, esw, E, N);
  k_nodeprep<<<(N + 3) / 4, 256, 0, stream>>>(x, scl1, xnk1, N, cp);
  k_biaspt_all<<<8, 128, 0, stream>>>(eb1, eb2, biasb, cp);

  const int aggBlocks = ((ET + CHUNK - 1) / CHUNK + 3) / 4;
  const int poolBlocks = ((N + NCH - 1) / NCH + 3) / 4;
  const size_t aggBytes = (size_t)N * 128 * sizeof(float);

  for (int ex = 0; ex < 4; ex++) {
    float kv = cp.k[ex], sk = cp.sk[ex], mxn = cp.mx[ex];
    // layer 1 (expmap0 fused via per-node scale)
    k_matpre<<<(N + 63) / 64, 256, 0, stream>>>(x, scl1 + (size_t)ex * N, xnk1 + (size_t)ex * N,
                                                ew1 + (size_t)ex * 16384, biasb + (ex * 2) * 132,
                                                tbh, N, kv, sk, mxn);
    hipMemsetAsync(agg, 0, aggBytes, stream);
    k_aggE<<<aggBlocks, 256, 0, stream>>>(esw, csroff, (const f16x2*)tbh, agg, ET, N);
    k_postnorm<<<(N + 3) / 4, 256, 0, stream>>>(agg, scl2, xnk2, N, kv, sk, mxn);
    // layer 2 (input = raw agg, expmap0 fused via scl2)
    k_matpre<<<(N + 63) / 64, 256, 0, stream>>>(agg, scl2, xnk2, ew2 + (size_t)ex * 16384,
                                                biasb + (ex * 2 + 1) * 132, tbh, N, kv, sk, mxn);
    hipMemsetAsync(agg, 0, aggBytes, stream);
    k_aggE<<<aggBlocks, 256, 0, stream>>>(esw, csroff, (const f16x2*)tbh, agg, ET, N);
    k_postpool<<<poolBlocks, 256, 0, stream>>>(agg, boff, feats, ex, N, kv, sk, mxn);
  }

  // gate GCN
  k_gate1<<<(N + 63) / 64, 256, 0, stream>>>(x, gw1, m1, N);
  k_agg_relu32<<<(N + 3) / 4, 256, 0, stream>>>(m1, csroff, esw, gb1, g1, N);
  k_gate2<<<(N + 63) / 64, 256, 0, stream>>>(g1, gw2, tbh, N);
  hipMemsetAsync(agg, 0, aggBytes, stream);
  k_aggE<<<aggBlocks, 256, 0, stream>>>(esw, csroff, (const f16x2*)tbh, agg, ET, N);
  k_postgate<<<poolBlocks, 256, 0, stream>>>(agg, boff, gb2, hg, N);

  k_final<<<B, 128, 0, stream>>>(feats, hg, counts, gu, traw, out, cp);

  (void)in_sizes; (void)n_in; (void)out_size; (void)ws_size;
}

// Round 5
// 1375.295 us; speedup vs baseline: 1.6540x; 1.3023x over previous
//
#include <hip/hip_runtime.h>
#include <math.h>

// ---------------- constants ----------------
#define NN 50000
#define EE 800000
#define ETOT (EE + NN)
#define BB 128
#define DIM 128
#define GHID 32
#define CHUNK 128
#define PCH 16

typedef _Float16 f16;
typedef _Float16 f16x2 __attribute__((ext_vector_type(2)));
typedef _Float16 f16x8 __attribute__((ext_vector_type(8)));

struct CurvPack {
  float k[4], sk[4], mx[4];
};

// ---------------- device math helpers ----------------
__device__ __forceinline__ float wsum64(float v) {
#pragma unroll
  for (int m = 32; m; m >>= 1) v += __shfl_xor(v, m, 64);
  return v;
}

__device__ __forceinline__ float tan_k_d(float x, float kv, float sk) {
  if (kv > 0.f) return tanf(x * sk) / sk;
  if (kv < 0.f) return tanhf(x * sk) / sk;
  return x;
}

__device__ __forceinline__ float artan_k_d(float x, float kv, float sk) {
  if (kv > 0.f) return atanf(x * sk) / sk;
  if (kv < 0.f) {
    float t = x * sk;
    t = fminf(fmaxf(t, -1.f + 1e-7f), 1.f - 1e-7f);
    return atanhf(t) / sk;
  }
  return x;
}

__device__ __forceinline__ float proj_scale_d(float n, float kv, float maxn) {
  if (kv < 0.f && n > maxn) return maxn / n;
  return 1.f;
}

// ---------------- graph preprocessing ----------------
__global__ void k_init(float* __restrict__ deg, int n) {
  int i = blockIdx.x * 256 + threadIdx.x;
  if (i < n) deg[i] = 1.0f;  // self loop
}

// counts + batch offsets via binary search (batch is sorted; no atomics)
__global__ void k_counts(const int* __restrict__ batch, int* __restrict__ boff,
                         float* __restrict__ counts, int n) {
  int b = threadIdx.x;  // 0..255
  if (b <= 128) {
    int lo = 0, hi = n;
    while (lo < hi) {
      int mid = (lo + hi) >> 1;
      if (batch[mid] < b) lo = mid + 1; else hi = mid;
    }
    boff[b] = lo;
  }
  __syncthreads();
  if (b < 128) counts[b] = (float)(boff[b + 1] - boff[b]);
}

__global__ void k_deg(const int* __restrict__ ei, float* __restrict__ deg, int e) {
  int i = blockIdx.x * 256 + threadIdx.x;
  if (i < e) atomicAdd(&deg[ei[e + i]], 1.0f);  // col = edge_index[1]
}

__global__ void k_dinv(float* __restrict__ deg, int* __restrict__ ideg, int n) {
  int i = blockIdx.x * 256 + threadIdx.x;
  if (i < n) {
    float d = deg[i];
    ideg[i] = (int)(d + 0.5f);
    deg[i] = 1.0f / sqrtf(d);  // deg buffer becomes dinv
  }
}

// single-block exclusive scan of ideg -> off[0..n], cursor copy
__global__ void k_scan(const int* __restrict__ ideg, int* __restrict__ off,
                       int* __restrict__ cursor, int n) {
  __shared__ int wsh[16];
  int tid = threadIdx.x;
  int lane = tid & 63;
  int w = tid >> 6;
  int carry = 0;
  for (int base = 0; base < n; base += 1024) {
    int idx = base + tid;
    int v = (idx < n) ? ideg[idx] : 0;
    int x = v;
#pragma unroll
    for (int o2 = 1; o2 < 64; o2 <<= 1) {
      int t2 = __shfl_up(x, o2, 64);
      if (lane >= o2) x += t2;
    }
    if (lane == 63) wsh[w] = x;
    __syncthreads();
    if (tid < 16) {
      int s = wsh[tid];
#pragma unroll
      for (int o2 = 1; o2 < 16; o2 <<= 1) {
        int t2 = __shfl_up(s, o2, 64);
        if (lane >= o2) s += t2;
      }
      wsh[tid] = s;
    }
    __syncthreads();
    int woff = carry + (w ? wsh[w - 1] : 0);
    int incl = woff + x;
    if (idx < n) {
      off[idx] = incl - v;
      cursor[idx] = incl - v;
    }
    carry += wsh[15];
    __syncthreads();
  }
  if (tid == 0) off[n] = carry;
}

// place edges: esw[p] = (src, weight_bits) at dst-sorted position
__global__ void k_place(const int* __restrict__ ei, const float* __restrict__ dinv,
                        int* __restrict__ cursor, int2* __restrict__ esw, int e, int n) {
  int i = blockIdx.x * 256 + threadIdx.x;
  int et = e + n;
  if (i >= et) return;
  int r_, c_;
  if (i < e) {
    r_ = ei[i];
    c_ = ei[e + i];
  } else {
    r_ = i - e;
    c_ = i - e;
  }
  int p = atomicAdd(&cursor[c_], 1);
  esw[p] = make_int2(r_, __float_as_int(dinv[r_] * dinv[c_]));
}

// ---------------- per-node prep: raw norm of x + all 4 expert expmap0 scales ----------------
__global__ void k_nodeprep(const float* __restrict__ x, float* __restrict__ scl,
                           float* __restrict__ xnk, int n, CurvPack cp) {
  int wid = blockIdx.x * 4 + (threadIdx.x >> 6);
  int lane = threadIdx.x & 63;
  if (wid >= n) return;
  float2 v = ((const float2*)x)[(size_t)wid * 64 + lane];
  float n2 = wsum64(v.x * v.x + v.y * v.y);
  float nraw = sqrtf(n2);
  if (lane < 4) {
    float kv = cp.k[lane], sk = cp.sk[lane], maxn = cp.mx[lane];
    float nnv = fmaxf(nraw, 1e-15f);
    float tk = tan_k_d(nnv, kv, sk);
    float s = tk / nnv;
    float pn = fmaxf(fabsf(tk) * (nraw / nnv), 1e-15f);
    float ps = proj_scale_d(pn, kv, maxn);
    scl[(size_t)lane * n + wid] = s * ps;
    xnk[(size_t)lane * n + wid] = pn * ps;
  }
}

// ---------------- bias points: expmap0(b) for all 8 (expert,layer) pairs ----------------
__global__ void k_biaspt_all(const float* __restrict__ eb1, const float* __restrict__ eb2,
                             float* __restrict__ biasb, CurvPack cp) {
  __shared__ float l2[2];
  int blk = blockIdx.x;  // ex*2 + layer
  int ex = blk >> 1, layer = blk & 1;
  float kv = cp.k[ex], sk = cp.sk[ex], maxn = cp.mx[ex];
  const float* b = (layer ? eb2 : eb1) + ex * 128;
  float* outb = biasb + blk * 132;
  int j = threadIdx.x;  // 0..127
  float v = b[j];
  float n2 = wsum64(v * v);
  if ((j & 63) == 0) l2[j >> 6] = n2;
  __syncthreads();
  n2 = l2[0] + l2[1];
  float nraw = sqrtf(n2);
  float nnv = fmaxf(nraw, 1e-15f);
  float tk = tan_k_d(nnv, kv, sk);
  float s = tk / nnv;
  float pn = fmaxf(fabsf(tk) * (nraw / nnv), 1e-15f);
  float ps = proj_scale_d(pn, kv, maxn);
  float bp = ps * s * v;
  outb[j] = bp;
  float y2v = wsum64(bp * bp);
  __syncthreads();
  if ((j & 63) == 0) l2[j >> 6] = y2v;
  __syncthreads();
  if (j == 0) outb[128] = l2[0] + l2[1];
}

// ---------------- expert GEMM + mobius pointwise -> t (fp16 out) ----------------
__global__ __launch_bounds__(256) void k_matpre(
    const float* __restrict__ xmx, const float* __restrict__ scale,
    const float* __restrict__ xnorm, const float* __restrict__ W,
    const float* __restrict__ biasb, f16* __restrict__ tout, int n, float kv, float sk,
    float maxn) {
  __shared__ float xT[64][68];
  __shared__ float Wt[64][132];
  int tid = threadIdx.x;
  int n0 = blockIdx.x * 64;
  int c = tid & 15, r = tid >> 4;

  float acc[4][8];
#pragma unroll
  for (int i = 0; i < 4; i++)
#pragma unroll
    for (int jj = 0; jj < 8; jj++) acc[i][jj] = 0.f;

  for (int kc = 0; kc < 2; kc++) {
    if (kc) __syncthreads();
#pragma unroll
    for (int it = 0; it < 32; it++) {
      int u = tid + it * 256;
      int j = u >> 6, kd = u & 63;
      Wt[kd][j] = W[j * 128 + kc * 64 + kd];
    }
#pragma unroll
    for (int it = 0; it < 4; it++) {
      int u = tid + it * 256;
      int node = u >> 4, c4 = u & 15;
      float4 v = make_float4(0.f, 0.f, 0.f, 0.f);
      if (n0 + node < n) {
        v = ((const float4*)xmx)[(size_t)(n0 + node) * 32 + kc * 16 + c4];
        if (scale) {
          float sc = scale[n0 + node];
          v.x *= sc; v.y *= sc; v.z *= sc; v.w *= sc;
        }
      }
      xT[4 * c4 + 0][node] = v.x;
      xT[4 * c4 + 1][node] = v.y;
      xT[4 * c4 + 2][node] = v.z;
      xT[4 * c4 + 3][node] = v.w;
    }
    __syncthreads();
#pragma unroll 8
    for (int kd = 0; kd < 64; kd++) {
      float4 av = *(const float4*)&xT[kd][r * 4];
      float4 b0 = *(const float4*)&Wt[kd][c * 8];
      float4 b1 = *(const float4*)&Wt[kd][c * 8 + 4];
      float a[4] = {av.x, av.y, av.z, av.w};
      float bbv[8] = {b0.x, b0.y, b0.z, b0.w, b1.x, b1.y, b1.z, b1.w};
#pragma unroll
      for (int i = 0; i < 4; i++)
#pragma unroll
        for (int jj = 0; jj < 8; jj++) acc[i][jj] = fmaf(a[i], bbv[jj], acc[i][jj]);
    }
  }

  float bp[8];
#pragma unroll
  for (int jj = 0; jj < 8; jj++) bp[jj] = biasb[c * 8 + jj];
  float y2 = biasb[128];

  float mxn2[4], sab[4], mbp[4];
#pragma unroll
  for (int i = 0; i < 4; i++) {
    float s0 = 0.f, s1 = 0.f, s2v = 0.f;
#pragma unroll
    for (int jj = 0; jj < 8; jj++) {
      float v = acc[i][jj];
      s0 = fmaf(v, v, s0);
      s1 += fabsf(v);
      s2v = fmaf(v, bp[jj], s2v);
    }
    mxn2[i] = s0;
    sab[i] = s1;
    mbp[i] = s2v;
  }
#pragma unroll
  for (int m = 1; m < 16; m <<= 1) {
#pragma unroll
    for (int i = 0; i < 4; i++) {
      mxn2[i] += __shfl_xor(mxn2[i], m, 64);
      sab[i] += __shfl_xor(sab[i], m, 64);
      mbp[i] += __shfl_xor(mbp[i], m, 64);
    }
  }

  float As[4], Cs[4];
#pragma unroll
  for (int i = 0; i < 4; i++) {
    int node = n0 + r * 4 + i;
    float xnr = xnorm[node < n ? node : (n - 1)];
    float xn = fmaxf(xnr, 1e-15f);
    float mxraw = sqrtf(mxn2[i]);
    float mxv = fmaxf(mxraw, 1e-15f);
    float ar = artan_k_d(xn, kv, sk);
    float c1 = tan_k_d(mxv / xn * ar, kv, sk);
    float s = (sab[i] == 0.f) ? 0.f : c1 / mxv;
    float pn = fmaxf(fabsf(c1) * (mxraw / mxv), 1e-15f);
    float ps = (sab[i] == 0.f) ? 1.f : proj_scale_d(pn, kv, maxn);
    s *= ps;
    float x2 = (s * s) * mxn2[i];
    float xy = s * mbp[i];
    float A = 1.f - 2.f * kv * xy - kv * y2;
    float Cc = 1.f + kv * x2;
    float den = fmaxf(1.f - 2.f * kv * xy + (kv * kv) * x2 * y2, 1e-15f);
    As[i] = A * s / den;
    Cs[i] = Cc / den;
  }

  float hb[4][8];
  float hb2[4];
#pragma unroll
  for (int i = 0; i < 4; i++) {
    float s0 = 0.f;
#pragma unroll
    for (int jj = 0; jj < 8; jj++) {
      float v = fmaf(As[i], acc[i][jj], Cs[i] * bp[jj]);
      hb[i][jj] = v;
      s0 = fmaf(v, v, s0);
    }
    hb2[i] = s0;
  }
#pragma unroll
  for (int m = 1; m < 16; m <<= 1) {
#pragma unroll
    for (int i = 0; i < 4; i++) hb2[i] += __shfl_xor(hb2[i], m, 64);
  }

#pragma unroll
  for (int i = 0; i < 4; i++) {
    int node = n0 + r * 4 + i;
    if (node >= n) continue;
    float nraw = sqrtf(hb2[i]);
    float ps2 = proj_scale_d(fmaxf(nraw, 1e-15f), kv, maxn);
    float nh = fmaxf(ps2 * nraw, 1e-15f);
    float L = artan_k_d(nh, kv, sk) / nh * ps2;
    f16x8 hv;
#pragma unroll
    for (int jj = 0; jj < 8; jj++) hv[jj] = (f16)(L * hb[i][jj]);
    *((f16x8*)(tout + (size_t)node * 128) + c) = hv;
  }
}

// ---------------- edge-sweep aggregation: agg[dst] += w * t[src] (fp16 rows) ----------------
__global__ __launch_bounds__(256) void k_aggE(const int2* __restrict__ esw,
                                              const int* __restrict__ off,
                                              const f16x2* __restrict__ t,
                                              float* __restrict__ agg, int etot, int n) {
  int gw = blockIdx.x * 4 + (threadIdx.x >> 6);
  int lane = threadIdx.x & 63;
  int e0 = gw * CHUNK;
  if (e0 >= etot) return;
  int e1 = min(e0 + CHUNK, etot);
  // binary search: largest cur with off[cur] <= e0
  int lo = 0, hi = n;
  while (hi - lo > 1) {
    int mid = (lo + hi) >> 1;
    if (off[mid] <= e0) lo = mid; else hi = mid;
  }
  int cur = lo;
  int runStart = off[cur];
  int eend = off[cur + 1];
  float ax = 0.f, ay = 0.f;
  int j = e0;
  while (j < e1) {
    if (j + 8 <= e1 && eend >= j + 8) {
      int2 m[8];
#pragma unroll
      for (int q = 0; q < 8; q++) m[q] = esw[j + q];
      f16x2 r[8];
#pragma unroll
      for (int q = 0; q < 8; q++) {
        int s = __builtin_amdgcn_readfirstlane(m[q].x);
        r[q] = t[(size_t)s * 64 + lane];
      }
#pragma unroll
      for (int q = 0; q < 8; q++) {
        float w = __int_as_float(m[q].y);
        ax = fmaf(w, (float)r[q][0], ax);
        ay = fmaf(w, (float)r[q][1], ay);
      }
      j += 8;
    } else if (j + 4 <= e1 && eend >= j + 4) {
      int2 m[4];
#pragma unroll
      for (int q = 0; q < 4; q++) m[q] = esw[j + q];
      f16x2 r[4];
#pragma unroll
      for (int q = 0; q < 4; q++) {
        int s = __builtin_amdgcn_readfirstlane(m[q].x);
        r[q] = t[(size_t)s * 64 + lane];
      }
#pragma unroll
      for (int q = 0; q < 4; q++) {
        float w = __int_as_float(m[q].y);
        ax = fmaf(w, (float)r[q][0], ax);
        ay = fmaf(w, (float)r[q][1], ay);
      }
      j += 4;
    } else {
      if (j == eend) {
        float* dp = agg + (size_t)cur * 128 + lane * 2;
        if (runStart >= e0) {
          dp[0] = ax;
          dp[1] = ay;
        } else {
          atomicAdd(dp, ax);
          atomicAdd(dp + 1, ay);
        }
        ax = ay = 0.f;
        runStart = j;
        cur++;
        eend = off[cur + 1];
      }
      int2 m = esw[j];
      int s = __builtin_amdgcn_readfirstlane(m.x);
      f16x2 rv = t[(size_t)s * 64 + lane];
      float w = __int_as_float(m.y);
      ax = fmaf(w, (float)rv[0], ax);
      ay = fmaf(w, (float)rv[1], ay);
      j++;
    }
  }
  float* dp = agg + (size_t)cur * 128 + lane * 2;
  if (runStart >= e0 && eend <= e1) {
    dp[0] = ax;
    dp[1] = ay;
  } else {
    atomicAdd(dp, ax);
    atomicAdd(dp + 1, ay);
  }
}

// ---------------- post-agg: per-node expmap0 scale (for layer-2 matpre) ----------------
__global__ void k_postnorm(const float* __restrict__ agg, float* __restrict__ scl,
                           float* __restrict__ xnk, int n, float kv, float sk, float maxn) {
  int wid = blockIdx.x * 4 + (threadIdx.x >> 6);
  int lane = threadIdx.x & 63;
  if (wid >= n) return;
  float2 v = ((const float2*)agg)[(size_t)wid * 64 + lane];
  float n2 = wsum64(fmaf(v.x, v.x, v.y * v.y));
  float nraw = sqrtf(n2);
  float nnv = fmaxf(nraw, 1e-15f);
  float tk = tan_k_d(nnv, kv, sk);
  float s = tk / nnv;
  float pn = fmaxf(fabsf(tk) * (nraw / nnv), 1e-15f);
  float ps = proj_scale_d(pn, kv, maxn);
  if (lane == 0) {
    scl[wid] = s * ps;
    xnk[wid] = pn * ps;
  }
}

// ---------------- post-agg: per-node pooling scale sc = logmap0 o expmap0 ----------------
__global__ void k_postscale(const float* __restrict__ agg, float* __restrict__ scpool, int n,
                            float kv, float sk, float maxn) {
  int wid = blockIdx.x * 4 + (threadIdx.x >> 6);
  int lane = threadIdx.x & 63;
  if (wid >= n) return;
  float2 v = ((const float2*)agg)[(size_t)wid * 64 + lane];
  float n2 = wsum64(fmaf(v.x, v.x, v.y * v.y));
  float nraw = sqrtf(n2);
  float nnv = fmaxf(nraw, 1e-15f);
  float tk = tan_k_d(nnv, kv, sk);
  float s = tk / nnv;
  float pn = fmaxf(fabsf(tk) * (nraw / nnv), 1e-15f);
  float ps = proj_scale_d(pn, kv, maxn);
  s *= ps;
  float nh = fmaxf(pn * ps, 1e-15f);
  float sc = artan_k_d(nh, kv, sk) / nh * s;
  if (lane == 0) scpool[wid] = sc;
}

// ---------------- strip pooling: feats[b] += sc[node]*agg[node] ----------------
__global__ void k_pooladd(const float* __restrict__ agg, const float* __restrict__ scpool,
                          const int* __restrict__ boff, float* __restrict__ feats, int ex,
                          int n) {
  int gw = blockIdx.x * 4 + (threadIdx.x >> 6);
  int lane = threadIdx.x & 63;
  int n0 = gw * PCH;
  if (n0 >= n) return;
  int n1 = min(n0 + PCH, n);
  int lo = 0, hi = 128;
  while (hi - lo > 1) {
    int mid = (lo + hi) >> 1;
    if (boff[mid] <= n0) lo = mid; else hi = mid;
  }
  int cb = lo;
  int bend = boff[cb + 1];
  float ax = 0.f, ay = 0.f;
  for (int node = n0; node < n1; node++) {
    while (node == bend) {
      float* dp = &feats[(size_t)cb * 512 + ex * 128 + lane * 2];
      atomicAdd(dp, ax);
      atomicAdd(dp + 1, ay);
      ax = ay = 0.f;
      cb++;
      bend = boff[cb + 1];
    }
    float sc = scpool[node];
    float2 v = ((const float2*)agg)[(size_t)node * 64 + lane];
    ax = fmaf(sc, v.x, ax);
    ay = fmaf(sc, v.y, ay);
  }
  float* dp = &feats[(size_t)cb * 512 + ex * 128 + lane * 2];
  atomicAdd(dp, ax);
  atomicAdd(dp + 1, ay);
}

// ---------------- strip pooling: hgate[b] += relu(agg[node]+bias) ----------------
__global__ void k_poolgate(const float* __restrict__ agg, const float* __restrict__ bias,
                           const int* __restrict__ boff, float* __restrict__ hgate, int n) {
  int gw = blockIdx.x * 4 + (threadIdx.x >> 6);
  int lane = threadIdx.x & 63;
  int n0 = gw * PCH;
  if (n0 >= n) return;
  int n1 = min(n0 + PCH, n);
  int lo = 0, hi = 128;
  while (hi - lo > 1) {
    int mid = (lo + hi) >> 1;
    if (boff[mid] <= n0) lo = mid; else hi = mid;
  }
  int cb = lo;
  int bend = boff[cb + 1];
  float2 bb = ((const float2*)bias)[lane];
  float ax = 0.f, ay = 0.f;
  for (int node = n0; node < n1; node++) {
    while (node == bend) {
      float* dp = &hgate[(size_t)cb * 128 + lane * 2];
      atomicAdd(dp, ax);
      atomicAdd(dp + 1, ay);
      ax = ay = 0.f;
      cb++;
      bend = boff[cb + 1];
    }
    float2 v = ((const float2*)agg)[(size_t)node * 64 + lane];
    ax += fmaxf(v.x + bb.x, 0.f);
    ay += fmaxf(v.y + bb.y, 0.f);
  }
  float* dp = &hgate[(size_t)cb * 128 + lane * 2];
  atomicAdd(dp, ax);
  atomicAdd(dp + 1, ay);
}

// ---------------- gate GEMM 1: m1 = x @ gw1.T  [N,128] -> [N,32] ----------------
__global__ __launch_bounds__(256) void k_gate1(const float* __restrict__ x,
                                               const float* __restrict__ gw1,
                                               float* __restrict__ m1, int n) {
  __shared__ float xT[64][68];
  __shared__ float Wt[64][36];
  int tid = threadIdx.x;
  int n0 = blockIdx.x * 64;
  int c = tid & 7, r = tid >> 3;
  float acc[2][4];
#pragma unroll
  for (int i = 0; i < 2; i++)
#pragma unroll
    for (int jj = 0; jj < 4; jj++) acc[i][jj] = 0.f;

  for (int kc = 0; kc < 2; kc++) {
    if (kc) __syncthreads();
#pragma unroll
    for (int it = 0; it < 8; it++) {
      int u = tid + it * 256;
      int j = u >> 6, kd = u & 63;
      Wt[kd][j] = gw1[j * 128 + kc * 64 + kd];
    }
#pragma unroll
    for (int it = 0; it < 4; it++) {
      int u = tid + it * 256;
      int node = u >> 4, c4 = u & 15;
      float4 v = make_float4(0.f, 0.f, 0.f, 0.f);
      if (n0 + node < n) v = ((const float4*)x)[(size_t)(n0 + node) * 32 + kc * 16 + c4];
      xT[4 * c4 + 0][node] = v.x;
      xT[4 * c4 + 1][node] = v.y;
      xT[4 * c4 + 2][node] = v.z;
      xT[4 * c4 + 3][node] = v.w;
    }
    __syncthreads();
#pragma unroll 8
    for (int kd = 0; kd < 64; kd++) {
      float2 av = *(const float2*)&xT[kd][r * 2];
      float4 bv = *(const float4*)&Wt[kd][c * 4];
      float a[2] = {av.x, av.y};
      float bbv[4] = {bv.x, bv.y, bv.z, bv.w};
#pragma unroll
      for (int i = 0; i < 2; i++)
#pragma unroll
        for (int jj = 0; jj < 4; jj++) acc[i][jj] = fmaf(a[i], bbv[jj], acc[i][jj]);
    }
  }
#pragma unroll
  for (int i = 0; i < 2; i++) {
    int node = n0 + r * 2 + i;
    if (node >= n) continue;
    ((float4*)m1)[(size_t)node * 8 + c] = make_float4(acc[i][0], acc[i][1], acc[i][2], acc[i][3]);
  }
}

// ---------------- gate GEMM 2: m2 = g1 @ gw2.T  [N,32] -> [N,128] fp16 out ----------------
__global__ __launch_bounds__(256) void k_gate2(const float* __restrict__ g1,
                                               const float* __restrict__ gw2,
                                               f16* __restrict__ m2, int n) {
  __shared__ float xT[32][68];
  __shared__ float Wt[32][132];
  int tid = threadIdx.x;
  int n0 = blockIdx.x * 64;
  int c = tid & 15, r = tid >> 4;
  float acc[4][8];
#pragma unroll
  for (int i = 0; i < 4; i++)
#pragma unroll
    for (int jj = 0; jj < 8; jj++) acc[i][jj] = 0.f;

#pragma unroll
  for (int it = 0; it < 16; it++) {
    int u = tid + it * 256;
    int j = u >> 5, kd = u & 31;
    Wt[kd][j] = gw2[j * 32 + kd];
  }
#pragma unroll
  for (int it = 0; it < 2; it++) {
    int u = tid + it * 256;
    int node = u >> 3, c4 = u & 7;
    float4 v = make_float4(0.f, 0.f, 0.f, 0.f);
    if (n0 + node < n) v = ((const float4*)g1)[(size_t)(n0 + node) * 8 + c4];
    xT[4 * c4 + 0][node] = v.x;
    xT[4 * c4 + 1][node] = v.y;
    xT[4 * c4 + 2][node] = v.z;
    xT[4 * c4 + 3][node] = v.w;
  }
  __syncthreads();
#pragma unroll 8
  for (int kd = 0; kd < 32; kd++) {
    float4 av = *(const float4*)&xT[kd][r * 4];
    float4 b0 = *(const float4*)&Wt[kd][c * 8];
    float4 b1 = *(const float4*)&Wt[kd][c * 8 + 4];
    float a[4] = {av.x, av.y, av.z, av.w};
    float bbv[8] = {b0.x, b0.y, b0.z, b0.w, b1.x, b1.y, b1.z, b1.w};
#pragma unroll
    for (int i = 0; i < 4; i++)
#pragma unroll
      for (int jj = 0; jj < 8; jj++) acc[i][jj] = fmaf(a[i], bbv[jj], acc[i][jj]);
  }
#pragma unroll
  for (int i = 0; i < 4; i++) {
    int node = n0 + r * 4 + i;
    if (node >= n) continue;
    f16x8 hv;
#pragma unroll
    for (int jj = 0; jj < 8; jj++) hv[jj] = (f16)acc[i][jj];
    *((f16x8*)(m2 + (size_t)node * 128) + c) = hv;
  }
}

// ---------------- gate aggregation dim32 + bias + relu (node-parallel) ----------------
__global__ void k_agg_relu32(const float* __restrict__ m1, const int* __restrict__ off,
                             const int2* __restrict__ esw, const float* __restrict__ bias,
                             float* __restrict__ g1, int n) {
  int node = blockIdx.x * 4 + (threadIdx.x >> 6);
  int lane = threadIdx.x & 63;
  if (node >= n) return;
  int grp = lane >> 3, l8 = lane & 7;
  int e0 = off[node], e1 = off[node + 1];
  float4 acc = make_float4(0.f, 0.f, 0.f, 0.f);
  for (int base = e0 + grp; base < e1; base += 8) {
    int2 me = esw[base];
    int ss = me.x;
    float ww = __int_as_float(me.y);
    float4 tv = ((const float4*)m1)[(size_t)ss * 8 + l8];
    acc.x = fmaf(ww, tv.x, acc.x);
    acc.y = fmaf(ww, tv.y, acc.y);
    acc.z = fmaf(ww, tv.z, acc.z);
    acc.w = fmaf(ww, tv.w, acc.w);
  }
#pragma unroll
  for (int m = 8; m <= 32; m <<= 1) {
    acc.x += __shfl_xor(acc.x, m, 64);
    acc.y += __shfl_xor(acc.y, m, 64);
    acc.z += __shfl_xor(acc.z, m, 64);
    acc.w += __shfl_xor(acc.w, m, 64);
  }
  if (grp == 0) {
    float4 bb = ((const float4*)bias)[l8];
    float4 o = make_float4(fmaxf(acc.x + bb.x, 0.f), fmaxf(acc.y + bb.y, 0.f),
                           fmaxf(acc.z + bb.z, 0.f), fmaxf(acc.w + bb.w, 0.f));
    ((float4*)g1)[(size_t)node * 8 + l8] = o;
  }
}

// ---------------- final: distance gate + softmax + outputs ----------------
__global__ __launch_bounds__(128) void k_final(const float* __restrict__ feats,
                                               const float* __restrict__ hgate,
                                               const float* __restrict__ counts,
                                               const float* __restrict__ gate_u,
                                               const float* __restrict__ tau_raw,
                                               float* __restrict__ out, CurvPack cp) {
  __shared__ float l2[2];
  int b = blockIdx.x;
  int j = threadIdx.x;
  float cnt = fmaxf(counts[b], 1.f);
  float hg = hgate[(size_t)b * 128 + j] / cnt;

  auto bsum = [&](float v) -> float {
    v = wsum64(v);
    __syncthreads();
    if ((j & 63) == 0) l2[j >> 6] = v;
    __syncthreads();
    return l2[0] + l2[1];
  };

  float nhg2 = bsum(hg * hg);
  float nhgraw = sqrtf(nhg2);
  float nhg = fmaxf(nhgraw, 1e-15f);

  float d[4], tau[4];
#pragma unroll
  for (int i = 0; i < 4; i++) {
    float kv = cp.k[i], sk = cp.sk[i], mxn = cp.mx[i];
    float tk = tan_k_d(nhg, kv, sk);
    float s = tk / nhg;
    float pn = fmaxf(fabsf(tk) * (nhgraw / nhg), 1e-15f);
    s *= proj_scale_d(pn, kv, mxn);
    float zk = s * hg;

    float u = gate_u[i * 128 + j];
    float nu2 = bsum(u * u);
    float nuraw = sqrtf(nu2);
    float nu = fmaxf(nuraw, 1e-15f);
    float tku = tan_k_d(nu, kv, sk);
    float su = tku / nu;
    float pnu = fmaxf(fabsf(tku) * (nuraw / nu), 1e-15f);
    su *= proj_scale_d(pnu, kv, mxn);
    float yk = su * u;

    float xv = -zk;
    float x2 = bsum(xv * xv);
    float y2 = bsum(yk * yk);
    float xy = bsum(xv * yk);
    float A = 1.f - 2.f * kv * xy - kv * y2;
    float C = 1.f + kv * x2;
    float den = fmaxf(1.f - 2.f * kv * xy + (kv * kv) * x2 * y2, 1e-15f);
    float ma = (A * xv + C * yk) / den;
    float m2 = bsum(ma * ma);
    float mraw = sqrtf(m2);
    float ps2 = proj_scale_d(fmaxf(mraw, 1e-15f), kv, mxn);
    float nm = fmaxf(ps2 * mraw, 1e-15f);
    d[i] = 2.f * artan_k_d(nm, kv, sk);

    float tr = tau_raw[i];
    tau[i] = fminf(fmaxf(log1pf(expf(tr)) + 0.05f, 0.05f), 10.f);
  }

  float xi[4];
  float mxv = -1e30f;
#pragma unroll
  for (int i = 0; i < 4; i++) {
    xi[i] = -d[i] / tau[i];
    mxv = fmaxf(mxv, xi[i]);
  }
  float es = 0.f, e[4];
#pragma unroll
  for (int i = 0; i < 4; i++) {
    e[i] = expf(xi[i] - mxv);
    es += e[i];
  }
  float w[4];
#pragma unroll
  for (int i = 0; i < 4; i++) w[i] = e[i] / es;

#pragma unroll
  for (int i = 0; i < 4; i++)
    out[(size_t)b * 512 + i * 128 + j] = feats[(size_t)b * 512 + i * 128 + j] / cnt * w[i];

  if (j < 4) {
    out[65536 + b * 4 + j] = w[j];
    out[66048 + b * 4 + j] = d[j];
  }
  if (b == 0 && j < 4) out[66560 + j] = tau[j];
}

// ---------------- host launcher ----------------
extern "C" void kernel_launch(void* const* d_in, const int* in_sizes, int n_in,
                              void* d_out, int out_size, void* d_ws, size_t ws_size,
                              hipStream_t stream) {
  const float* x = (const float*)d_in[0];
  const int* ei = (const int*)d_in[1];
  const int* batch = (const int*)d_in[2];
  const float* ew1 = (const float*)d_in[3];
  const float* eb1 = (const float*)d_in[4];
  const float* ew2 = (const float*)d_in[5];
  const float* eb2 = (const float*)d_in[6];
  const float* gw1 = (const float*)d_in[7];
  const float* gb1 = (const float*)d_in[8];
  const float* gw2 = (const float*)d_in[9];
  const float* gb2 = (const float*)d_in[10];
  const float* gu = (const float*)d_in[11];
  const float* traw = (const float*)d_in[12];
  float* out = (float*)d_out;

  const int N = NN, E = EE, ET = ETOT, B = BB;

  float* ws = (float*)d_ws;
  size_t o = 0;
  f16* tbh = (f16*)ws;      o += (size_t)N * 64;  // N*128 halfs (16B-aligned)
  float* agg = ws + o;      o += (size_t)N * 128;
  float* m1 = ws + o;       o += (size_t)N * 32;
  float* g1 = ws + o;       o += (size_t)N * 32;
  float* deg = ws + o;      o += N;  // becomes dinv
  float* scl1 = ws + o;     o += (size_t)4 * N;
  float* xnk1 = ws + o;     o += (size_t)4 * N;
  float* scl2 = ws + o;     o += N;
  float* xnk2 = ws + o;     o += N;
  float* scpool = ws + o;   o += N;
  float* counts = ws + o;   o += 256;
  float* feats = ws + o;    o += (size_t)B * 512;
  float* hg = ws + o;       o += (size_t)B * 128;
  float* biasb = ws + o;    o += 8 * 132;
  int* ideg = (int*)(ws + o);   o += N;
  int* csroff = (int*)(ws + o); o += N + 8;
  int* cursor = (int*)(ws + o); o += N;
  int* boff = (int*)(ws + o);   o += 136;
  int2* esw = (int2*)(ws + o);  o += (size_t)2 * ET;

  // zero: counts + feats + hg (contiguous)
  hipMemsetAsync(counts, 0, (256 + (size_t)B * 512 + (size_t)B * 128) * sizeof(float), stream);

  const double curvs[4] = {-1.0, 0.0, 1.0, -0.5};
  CurvPack cp;
  for (int i = 0; i < 4; i++) {
    double kd = curvs[i];
    double skd = sqrt(fabs(kd));
    cp.k[i] = (float)kd;
    cp.sk[i] = (float)skd;
    cp.mx[i] = (kd < 0) ? (float)((1.0 - 1e-5) / skd) : 3.0e38f;
  }

  k_init<<<(N + 255) / 256, 256, 0, stream>>>(deg, N);
  k_counts<<<1, 256, 0, stream>>>(batch, boff, counts, N);
  k_deg<<<(E + 255) / 256, 256, 0, stream>>>(ei, deg, E);
  k_dinv<<<(N + 255) / 256, 256, 0, stream>>>(deg, ideg, N);
  k_scan<<<1, 1024, 0, stream>>>(ideg, csroff, cursor, N);
  k_place<<<(ET + 255) / 256, 256, 0, stream>>>(ei, deg, cursor, esw, E, N);
  k_nodeprep<<<(N + 3) / 4, 256, 0, stream>>>(x, scl1, xnk1, N, cp);
  k_biaspt_all<<<8, 128, 0, stream>>>(eb1, eb2, biasb, cp);

  const int aggBlocks = ((ET + CHUNK - 1) / CHUNK + 3) / 4;
  const int poolBlocks = ((N + PCH - 1) / PCH + 3) / 4;
  const size_t aggBytes = (size_t)N * 128 * sizeof(float);

  for (int ex = 0; ex < 4; ex++) {
    float kv = cp.k[ex], sk = cp.sk[ex], mxn = cp.mx[ex];
    // layer 1 (expmap0 fused via per-node scale)
    k_matpre<<<(N + 63) / 64, 256, 0, stream>>>(x, scl1 + (size_t)ex * N, xnk1 + (size_t)ex * N,
                                                ew1 + (size_t)ex * 16384, biasb + (ex * 2) * 132,
                                                tbh, N, kv, sk, mxn);
    hipMemsetAsync(agg, 0, aggBytes, stream);
    k_aggE<<<aggBlocks, 256, 0, stream>>>(esw, csroff, (const f16x2*)tbh, agg, ET, N);
    k_postnorm<<<(N + 3) / 4, 256, 0, stream>>>(agg, scl2, xnk2, N, kv, sk, mxn);
    // layer 2 (input = raw agg, expmap0 fused via scl2)
    k_matpre<<<(N + 63) / 64, 256, 0, stream>>>(agg, scl2, xnk2, ew2 + (size_t)ex * 16384,
                                                biasb + (ex * 2 + 1) * 132, tbh, N, kv, sk, mxn);
    hipMemsetAsync(agg, 0, aggBytes, stream);
    k_aggE<<<aggBlocks, 256, 0, stream>>>(esw, csroff, (const f16x2*)tbh, agg, ET, N);
    k_postscale<<<(N + 3) / 4, 256, 0, stream>>>(agg, scpool, N, kv, sk, mxn);
    k_pooladd<<<poolBlocks, 256, 0, stream>>>(agg, scpool, boff, feats, ex, N);
  }

  // gate GCN
  k_gate1<<<(N + 63) / 64, 256, 0, stream>>>(x, gw1, m1, N);
  k_agg_relu32<<<(N + 3) / 4, 256, 0, stream>>>(m1, csroff, esw, gb1, g1, N);
  k_gate2<<<(N + 63) / 64, 256, 0, stream>>>(g1, gw2, tbh, N);
  hipMemsetAsync(agg, 0, aggBytes, stream);
  k_aggE<<<aggBlocks, 256, 0, stream>>>(esw, csroff, (const f16x2*)tbh, agg, ET, N);
  k_poolgate<<<poolBlocks, 256, 0, stream>>>(agg, gb2, boff, hg, N);

  k_final<<<B, 128, 0, stream>>>(feats, hg, counts, gu, traw, out, cp);

  (void)in_sizes; (void)n_in; (void)out_size; (void)ws_size;
}